// Round 9
// baseline (583.181 us; speedup 1.0000x reference)
//
#include <hip/hip_runtime.h>
#include <hip/hip_bf16.h>

#define NLAYERS 3
#define BB 32
#define LL 336
#define LP 352                 // K-padded stride for Tb16 / W1t (zeros in pad)
#define NN 321
#define EE 4
#define DHID 512
#define PP 96
#define STOT (BB*NN*LL)        // 3451392
#define MROWS (BB*NN)          // 10272
#define BPN ((size_t)BB*PP*NN) // 986112

typedef __attribute__((ext_vector_type(8))) short short8;
typedef __attribute__((ext_vector_type(4))) float float4v;

union BF { __hip_bfloat16 h; short s; };

__device__ __forceinline__ short f2b(float f) { BF u; u.h = __float2bfloat16(f); return u.s; }

__device__ __forceinline__ float fast_tanh(float y) {
    float e = __expf(2.0f * y);
    return 1.0f - 2.0f / (e + 1.0f);   // exact limits at +-inf
}
__device__ __forceinline__ float gelu_f(float x) {
    return 0.5f * x * (1.0f + fast_tanh(0.7978845608028654f * (x + 0.044715f * x * x * x)));
}
__device__ __forceinline__ float softplus_f(float x) {
    return fmaxf(x, 0.0f) + log1pf(expf(-fabsf(x)));
}

// ---------------- RevIN stats: mu/inv per (b,n); also zeros loss ----------------
__global__ __launch_bounds__(256) void revin_stats(
    const float* __restrict__ x, float* __restrict__ MU, float* __restrict__ IV,
    float* __restrict__ loss)
{
    int b = blockIdx.x, nt = blockIdx.y;
    int tid = threadIdx.x;
    if (b == 0 && nt == 0 && tid == 0) loss[0] = 0.0f;
    int ni = tid & 63, lc = tid >> 6;
    int n = nt * 64 + ni;
    float s = 0.f, ss = 0.f;
    if (n < NN) {
        const float* xp = x + ((size_t)b * LL + lc * 84) * NN + n;
        for (int l = 0; l < 84; ++l, xp += NN) {
            float v = *xp; s += v; ss = fmaf(v, v, ss);
        }
    }
    __shared__ float Ss[4][64], Sq[4][64];
    Ss[lc][ni] = s; Sq[lc][ni] = ss;
    __syncthreads();
    if (lc == 0 && n < NN) {
        float st = ((Ss[0][ni] + Ss[1][ni]) + Ss[2][ni]) + Ss[3][ni];
        float sq = ((Sq[0][ni] + Sq[1][ni]) + Sq[2][ni]) + Sq[3][ni];
        float mu  = st * (1.0f / LL);
        float var = sq * (1.0f / LL) - mu * mu;   // ddof=0
        float inv = 1.0f / sqrtf(var + 1e-5f);
        MU[b * NN + n] = mu;
        IV[b * NN + n] = inv;
    }
}

// ---------------- RevIN transpose+normalize: T (stride LL) + Tb16 (stride LP) ----------------
__global__ __launch_bounds__(256) void revin_tn(
    const float* __restrict__ x, const float* __restrict__ MU, const float* __restrict__ IV,
    float* __restrict__ T, short* __restrict__ Tb16)
{
    int b = blockIdx.x, nt = blockIdx.y, lt = blockIdx.z;
    int n0 = nt * 64, l0 = lt * 48;
    __shared__ float Ls[48][65];
    int tid = threadIdx.x;
    #pragma unroll
    for (int i = 0; i < 12; ++i) {
        int lin = tid + i * 256;
        int li = lin >> 6, ni = lin & 63;
        int n = n0 + ni;
        Ls[li][ni] = (n < NN) ? x[((size_t)b * LL + l0 + li) * NN + n] : 0.f;
    }
    __syncthreads();
    int r = tid >> 2, q = tid & 3;
    int n = n0 + r;
    if (n >= NN) return;
    float mu = MU[b * NN + n], iv = IV[b * NN + n];
    size_t rowf = (size_t)(b * NN + n) * LL + l0;
    size_t rowb = (size_t)(b * NN + n) * LP + l0;
    #pragma unroll
    for (int k = 0; k < 3; ++k) {
        int c = (q + 4 * k) * 4;
        float4 v;
        v.x = (Ls[c    ][r] - mu) * iv;
        v.y = (Ls[c + 1][r] - mu) * iv;
        v.z = (Ls[c + 2][r] - mu) * iv;
        v.w = (Ls[c + 3][r] - mu) * iv;
        *(float4*)&T[rowf + c] = v;
        union { short s[4]; uint2 u; } pk;
        pk.s[0] = f2b(v.x); pk.s[1] = f2b(v.y); pk.s[2] = f2b(v.z); pk.s[3] = f2b(v.w);
        *(uint2*)&Tb16[rowb + c] = pk.u;
    }
    if (lt == 6 && q == 3) {   // zero the K-pad cols 336..352
        size_t base = (size_t)(b * NN + n) * LP;
        *(uint4*)&Tb16[base + 336] = make_uint4(0, 0, 0, 0);
        *(uint4*)&Tb16[base + 344] = make_uint4(0, 0, 0, 0);
    }
}

// ---------------- tiled transpose+convert: dst[d][k(KS-strided)] <- bf16(src[k][d]) ----------------
__global__ __launch_bounds__(256) void wtrans_kernel(
    const float* __restrict__ src0, short* __restrict__ dst0, int K, int D, int KS)
{
    int le = blockIdx.z;
    const float* src = src0 + (size_t)le * K * D;
    short* dst = dst0 + (size_t)le * D * KS;
    int d0 = blockIdx.x * 64, k0 = blockIdx.y * 64;
    __shared__ short Ws[64][72];
    int tid = threadIdx.x;
    #pragma unroll
    for (int i = 0; i < 16; ++i) {
        int lin = tid + i * 256;
        int ki = lin >> 6, dj = lin & 63;
        int k = k0 + ki, d = d0 + dj;
        Ws[ki][dj] = (k < K && d < D) ? f2b(src[(size_t)k * D + d]) : (short)0;
    }
    __syncthreads();
    int di = tid >> 2, d = d0 + di;
    if (d >= D) return;
    #pragma unroll
    for (int kp = 0; kp < 2; ++kp) {
        int kj = ((tid & 3) + 4 * kp) * 8;
        if (k0 + kj >= KS) continue;
        union { short s[8]; uint4 u; } pk;
        #pragma unroll
        for (int j = 0; j < 8; ++j) pk.s[j] = Ws[kj + j][di];
        *(uint4*)(dst + (size_t)d * KS + k0 + kj) = pk.u;
    }
}

// ---------------- small convert for p1w/p2w (already [n][k]) ----------------
__global__ __launch_bounds__(256) void pcvt_kernel(
    const float* __restrict__ p1w, const float* __restrict__ p2w,
    short* __restrict__ p1wb, short* __restrict__ p2wb)
{
    int i = blockIdx.x * 256 + threadIdx.x;
    if (i < PP * LL) p1wb[i] = f2b(p1w[i]);
    else if (i < PP * LL + 2 * PP * PP) { int j = i - PP * LL; p2wb[j] = f2b(p2w[j]); }
}

// ---------------- gate features (layer 0 only): 8-way partial sums over n ----------------
__global__ __launch_bounds__(384) void gmean_part(
    const float* __restrict__ T, float* __restrict__ G8)
{
    int b = blockIdx.x, c = blockIdx.y;
    int l = threadIdx.x;
    if (l >= LL) return;
    int n_lo = c * 41, n_hi = (NN < n_lo + 41) ? NN : (n_lo + 41);
    const float* tp = T + ((size_t)b * NN + n_lo) * LL + l;
    float s = 0.f;
    for (int n = n_lo; n < n_hi; ++n, tp += LL) s += *tp;
    G8[((size_t)c * BB + b) * LL + l] = s;
}

__global__ __launch_bounds__(384) void gmean_red(
    const float* __restrict__ G8, float* __restrict__ G)
{
    int b = blockIdx.x;
    int l = threadIdx.x;
    if (l >= LL) return;
    float s = 0.f;
    #pragma unroll
    for (int c = 0; c < 8; ++c) s += G8[((size_t)c * BB + b) * LL + l];
    G[b * LL + l] = s;     // SUM (gating applies 1/NN)
}

// ---------------- noisy top-k gating + aux loss; G holds SUMS; zeroes G at end ----------------
__global__ __launch_bounds__(512) void gating_kernel(
    float* __restrict__ G, const float* __restrict__ wg,
    const float* __restrict__ wn, const float* __restrict__ noise,
    int* __restrict__ IDX, float* __restrict__ GV, float* __restrict__ loss)
{
    __shared__ float pc[BB][EE][4], pn[BB][EE][4];
    __shared__ float s_clean[BB][EE], s_nstd[BB][EE], s_noisy[BB][EE], s_gates[BB][EE];
    __shared__ float s_thr_in[BB], s_thr_out[BB];
    __shared__ float s_imp[EE], s_load[EE];
    int tid = threadIdx.x;
    {
        int b = tid >> 4, e = (tid >> 2) & 3, sub = tid & 3;
        float c = 0.f, nr = 0.f;
        const float* gp = G + b * LL;
        for (int l = sub * 84; l < sub * 84 + 84; ++l) {
            float gv = gp[l] * (1.0f / NN);
            c  = fmaf(gv, wg[l * EE + e], c);
            nr = fmaf(gv, wn[l * EE + e], nr);
        }
        pc[b][e][sub] = c; pn[b][e][sub] = nr;
    }
    __syncthreads();
    // all G reads done; zero G for next layer's accumulation
    for (int i2 = tid; i2 < BB * LL; i2 += 512) G[i2] = 0.0f;
    int b = tid >> 2, e = tid & 3;   // valid for tid < 128
    if (tid < 128) {
        float c  = ((pc[b][e][0] + pc[b][e][1]) + pc[b][e][2]) + pc[b][e][3];
        float nr = ((pn[b][e][0] + pn[b][e][1]) + pn[b][e][2]) + pn[b][e][3];
        float nstd  = softplus_f(nr) + 1e-2f;
        float noisy = fmaf(noise[b * EE + e], nstd, c);
        s_clean[b][e] = c; s_nstd[b][e] = nstd; s_noisy[b][e] = noisy;
    }
    __syncthreads();
    if (tid < 128 && e == 0) {
        float v[4];
        #pragma unroll
        for (int i = 0; i < 4; ++i) v[i] = s_noisy[b][i];
        int i0 = 0;
        for (int i = 1; i < 4; ++i) if (v[i] > v[i0]) i0 = i;
        int i1 = -1;
        for (int i = 0; i < 4; ++i) { if (i == i0) continue; if (i1 < 0 || v[i] > v[i1]) i1 = i; }
        float m3 = -1e30f;
        for (int i = 0; i < 4; ++i) { if (i == i0 || i == i1) continue; if (v[i] > m3) m3 = v[i]; }
        float e1  = expf(v[i1] - v[i0]);
        float invd = 1.0f / (1.0f + e1);
        #pragma unroll
        for (int i = 0; i < 4; ++i) s_gates[b][i] = 0.f;
        s_gates[b][i0] = invd;
        s_gates[b][i1] = e1 * invd;
        s_thr_in[b]  = m3;       // (k+1)-th value
        s_thr_out[b] = v[i1];    // k-th value
        IDX[2*b] = i0; IDX[2*b+1] = i1;
        GV[2*b] = invd; GV[2*b+1] = e1 * invd;
    }
    __syncthreads();
    if (tid < EE) {
        int ee = tid;
        float imp = 0.f, ld = 0.f;
        for (int bb2 = 0; bb2 < BB; ++bb2) {
            imp += s_gates[bb2][ee];
            float thr = (s_noisy[bb2][ee] > s_thr_in[bb2]) ? s_thr_in[bb2] : s_thr_out[bb2];
            float z = (s_clean[bb2][ee] - thr) / s_nstd[bb2][ee];
            ld += 0.5f * (1.0f + erff(z * 0.7071067811865476f));
        }
        s_imp[ee] = imp; s_load[ee] = ld;
    }
    __syncthreads();
    if (tid == 0) {
        float aux = 0.f;
        {
            float m = (s_imp[0] + s_imp[1] + s_imp[2] + s_imp[3]) * 0.25f;
            float var = 0.f;
            for (int i = 0; i < 4; ++i) { float d = s_imp[i] - m; var += d * d; }
            var *= (1.0f / 3.0f);
            aux += var / (m * m + 1e-10f);
        }
        {
            float m = (s_load[0] + s_load[1] + s_load[2] + s_load[3]) * 0.25f;
            float var = 0.f;
            for (int i = 0; i < 4; ++i) { float d = s_load[i] - m; var += d * d; }
            var *= (1.0f / 3.0f);
            aux += var / (m * m + 1e-10f);
        }
        loss[0] += 0.01f * aux;
    }
}

// ---------------- fused FC1+FC2 (MFMA): no Hs round-trip, atomic T accumulate ----------------
// grid (11, 64): x = m-tile(32), y = z = b*2+slot. 56KB LDS -> 2 blocks/CU.
__global__ __launch_bounds__(256, 2) void fc_fused(
    const short* __restrict__ Tb16, const short* __restrict__ W1t_l,
    const float* __restrict__ b1_l, const short* __restrict__ W2t_l,
    const float* __restrict__ b2_l, const int* __restrict__ IDX,
    const float* __restrict__ GV, float* __restrict__ T)
{
    int z = blockIdx.y;
    int b = z >> 1;
    int e = IDX[z];
    float g = GV[z];
    int m0 = blockIdx.x * 32;
    int tid = threadIdx.x;
    int wave = tid >> 6, lane = tid & 63, quad = lane >> 4, l16 = lane & 15;
    __shared__ short Al[32][360];   // A tile 32x352 (stride 360: ~2-way banks)
    __shared__ short Hl[32][536];   // H tile 32x512 (stride 536: ~2-way banks)

    {   // stage A once: 1408 uint4
        #pragma unroll
        for (int i = 0; i < 6; ++i) {
            int idx = tid + i * 256;
            if (idx < 1408) {
                int r = idx / 44, c = (idx - r * 44) * 8;
                *(uint4*)&Al[r][c] = *(const uint4*)(Tb16 + (size_t)(b * NN + m0 + r) * LP + c);
            }
        }
    }
    __syncthreads();

    float4v zero4 = {0.f, 0.f, 0.f, 0.f};
    // ---- fc1 phase: this wave computes H[:, dw..dw+128) ----
    int dw = wave * 128;
    {
        float4v acc1[2][8];
        #pragma unroll
        for (int i = 0; i < 2; ++i)
            #pragma unroll
            for (int j = 0; j < 8; ++j) acc1[i][j] = zero4;
        const short* Bb = W1t_l + ((size_t)e * DHID + dw + l16) * LP + quad * 8;
        #pragma unroll
        for (int ks = 0; ks < 11; ++ks) {
            int off = ks * 32;
            short8 af0 = *(const short8*)&Al[l16][off + quad * 8];
            short8 af1 = *(const short8*)&Al[16 + l16][off + quad * 8];
            #pragma unroll
            for (int nf = 0; nf < 8; ++nf) {
                short8 bf = *(const short8*)(Bb + (size_t)nf * 16 * LP + off);
                acc1[0][nf] = __builtin_amdgcn_mfma_f32_16x16x32_bf16(af0, bf, acc1[0][nf], 0, 0, 0);
                acc1[1][nf] = __builtin_amdgcn_mfma_f32_16x16x32_bf16(af1, bf, acc1[1][nf], 0, 0, 0);
            }
        }
        const float* b1e = b1_l + (size_t)e * DHID;
        #pragma unroll
        for (int nf = 0; nf < 8; ++nf) {
            int d = dw + nf * 16 + l16;
            float bias = b1e[d];
            #pragma unroll
            for (int mi = 0; mi < 2; ++mi)
                #pragma unroll
                for (int r = 0; r < 4; ++r)
                    Hl[mi * 16 + quad * 4 + r][d] = f2b(g * gelu_f(acc1[mi][nf][r] + bias));
        }
    }
    __syncthreads();

    // ---- fc2 phase: this wave owns l-frags f = wave + 4j ----
    float4v acc2[2][6];
    #pragma unroll
    for (int i = 0; i < 2; ++i)
        #pragma unroll
        for (int j = 0; j < 6; ++j) acc2[i][j] = zero4;
    #pragma unroll
    for (int ks = 0; ks < 16; ++ks) {
        int off = ks * 32;
        short8 af0 = *(const short8*)&Hl[l16][off + quad * 8];
        short8 af1 = *(const short8*)&Hl[16 + l16][off + quad * 8];
        #pragma unroll
        for (int j = 0; j < 6; ++j) {
            int colb = (wave + 4 * j) * 16;
            if (colb < LL) {    // wave-uniform branch
                short8 bf = *(const short8*)(W2t_l + ((size_t)e * LL + colb + l16) * DHID + off + quad * 8);
                acc2[0][j] = __builtin_amdgcn_mfma_f32_16x16x32_bf16(af0, bf, acc2[0][j], 0, 0, 0);
                acc2[1][j] = __builtin_amdgcn_mfma_f32_16x16x32_bf16(af1, bf, acc2[1][j], 0, 0, 0);
            }
        }
    }
    // ---- epilogue: atomic accumulate into T (+ this slot's share of bias) ----
    const float* b2e = b2_l + (size_t)e * LL;
    float* Tb = T + (size_t)b * NN * LL;
    #pragma unroll
    for (int j = 0; j < 6; ++j) {
        int colb = (wave + 4 * j) * 16;
        if (colb >= LL) continue;         // wave-uniform
        int gl = colb + l16;
        float bias2 = g * b2e[gl];
        #pragma unroll
        for (int mi = 0; mi < 2; ++mi) {
            #pragma unroll
            for (int r = 0; r < 4; ++r) {
                int gm = m0 + mi * 16 + quad * 4 + r;
                if (gm < NN)
                    unsafeAtomicAdd(&Tb[(size_t)gm * LL + gl], acc2[mi][j][r] + bias2);
            }
        }
    }
}

// ---------------- T -> Tb16 mirror refresh + gate-sum accumulation for next layer ----------------
// grid (11, 32): x = m-tile(32), y = b
__global__ __launch_bounds__(256) void t2b16_kernel(
    const float* __restrict__ T, short* __restrict__ Tb16, float* __restrict__ G)
{
    int mt = blockIdx.x, b = blockIdx.y;
    int m0 = mt * 32;
    int tid = threadIdx.x;
    #pragma unroll
    for (int i = 0; i < 11; ++i) {
        int idx = tid + i * 256;
        if (idx < 2688) {
            int r = idx / 84, cq = (idx - r * 84) * 4;
            int gm = m0 + r;
            if (gm < NN) {
                float4 v = *(const float4*)&T[(size_t)(b * NN + gm) * LL + cq];
                union { short s[4]; uint2 u; } pk;
                pk.s[0] = f2b(v.x); pk.s[1] = f2b(v.y); pk.s[2] = f2b(v.z); pk.s[3] = f2b(v.w);
                *(uint2*)&Tb16[(size_t)(b * NN + gm) * LP + cq] = pk.u;
            }
        }
    }
    if (tid < 64) {   // zero K-pad cols 336..352
        int r = tid >> 1, gm = m0 + r;
        if (gm < NN)
            *(uint4*)&Tb16[(size_t)(b * NN + gm) * LP + 336 + (tid & 1) * 8] = make_uint4(0, 0, 0, 0);
    }
    if (tid < 84) {   // column partial sums over this block's rows -> G (zeroed by gating)
        int rmax = NN - m0; if (rmax > 32) rmax = 32;
        float4 s = make_float4(0.f, 0.f, 0.f, 0.f);
        const float* tp = T + (size_t)(b * NN + m0) * LL + tid * 4;
        for (int r = 0; r < rmax; ++r, tp += LL) {
            float4 v = *(const float4*)tp;
            s.x += v.x; s.y += v.y; s.z += v.z; s.w += v.w;
        }
        float* gp = G + b * LL + tid * 4;
        unsafeAtomicAdd(gp + 0, s.x);
        unsafeAtomicAdd(gp + 1, s.y);
        unsafeAtomicAdd(gp + 2, s.z);
        unsafeAtomicAdd(gp + 3, s.w);
    }
}

// ---------------- fused projection head (MFMA), transposed phase 2 ----------------
__global__ __launch_bounds__(256) void proj_fused(
    const short* __restrict__ Tb16,
    const short* __restrict__ p1wb, const float* __restrict__ p1b,
    const short* __restrict__ p2wb, const float* __restrict__ p2b,
    float* __restrict__ out)
{
    __shared__ short smem[26624];                       // 52 KB, manually carved
    short (*Al)[40]   = (short (*)[40])smem;            // 64x40   (phase 1)
    short (*Bl1)[40]  = (short (*)[40])(smem + 2560);   // 96x40   (phase 1)
    short (*B2)[104]  = (short (*)[104])smem;           // 192x104 (phase 2, overlays Al/Bl1)
    short (*Hp)[104]  = (short (*)[104])(smem + 19968); // 64x104

    int m0 = blockIdx.x * 64;
    int tid = threadIdx.x;
    int wave = tid >> 6, lane = tid & 63, quad = lane >> 4, l16 = lane & 15;
    float4v zero4 = {0.f, 0.f, 0.f, 0.f};

    // ---- phase 1: 64 x 96 = T-tile @ p1w^T ----
    float4v acc1[6];
    #pragma unroll
    for (int i = 0; i < 6; ++i) acc1[i] = zero4;
    int am = tid >> 2, ako = (tid & 3) * 8;
    for (int k0 = 0; k0 < LL; k0 += 32) {
        {
            int gm = m0 + am;
            uint4 val = make_uint4(0, 0, 0, 0);
            if (gm < MROWS) val = *(const uint4*)(Tb16 + (size_t)gm * LP + k0 + ako);
            *(uint4*)&Al[am][ako] = val;
        }
        #pragma unroll
        for (int uu = 0; uu < 2; ++uu) {
            int u = tid + uu * 256;
            if (u < 384) {
                int n = u >> 2, ko = (u & 3) * 8;
                int gk = k0 + ko;
                uint4 val = make_uint4(0, 0, 0, 0);
                if (gk < LL) val = *(const uint4*)(p1wb + (size_t)n * LL + gk);
                *(uint4*)&Bl1[n][ko] = val;
            }
        }
        __syncthreads();
        short8 af = *(const short8*)&Al[wave * 16 + l16][quad * 8];
        #pragma unroll
        for (int ni = 0; ni < 6; ++ni) {
            short8 bfv = *(const short8*)&Bl1[ni * 16 + l16][quad * 8];
            acc1[ni] = __builtin_amdgcn_mfma_f32_16x16x32_bf16(af, bfv, acc1[ni], 0, 0, 0);
        }
        __syncthreads();
    }
    #pragma unroll
    for (int ni = 0; ni < 6; ++ni) {
        #pragma unroll
        for (int r = 0; r < 4; ++r) {
            int ml = wave * 16 + quad * 4 + r;
            int p = ni * 16 + l16;
            Hp[ml][p] = f2b(fast_tanh(acc1[ni][r] + p1b[p]));
        }
    }
    for (int u = tid; u < 192 * 12; u += 256) {
        int n = u / 12, ko = (u - n * 12) * 8;
        *(uint4*)&B2[n][ko] = *(const uint4*)(p2wb + (size_t)n * PP + ko);
    }
    __syncthreads();

    // ---- phase 2 (transposed): rows = c (192), cols = node (64), K = 96 ----
    float4v acc2[3][4];
    #pragma unroll
    for (int i = 0; i < 3; ++i)
        #pragma unroll
        for (int j = 0; j < 4; ++j) acc2[i][j] = zero4;
    #pragma unroll
    for (int kc = 0; kc < 3; ++kc) {
        int k0 = kc * 32 + quad * 8;
        short8 af[3], bfv[4];
        #pragma unroll
        for (int mi = 0; mi < 3; ++mi) af[mi] = *(const short8*)&B2[wave * 48 + mi * 16 + l16][k0];
        #pragma unroll
        for (int ni = 0; ni < 4; ++ni) bfv[ni] = *(const short8*)&Hp[ni * 16 + l16][k0];
        #pragma unroll
        for (int mi = 0; mi < 3; ++mi)
            #pragma unroll
            for (int ni = 0; ni < 4; ++ni)
                acc2[mi][ni] = __builtin_amdgcn_mfma_f32_16x16x32_bf16(af[mi], bfv[ni], acc2[mi][ni], 0, 0, 0);
    }
    int bqv[4], ndv[4]; bool okv[4];
    #pragma unroll
    for (int ni = 0; ni < 4; ++ni) {
        int gm = m0 + ni * 16 + l16;
        okv[ni] = (gm < MROWS);
        int bq = gm / NN;
        bqv[ni] = bq; ndv[ni] = gm - bq * NN;
    }
    #pragma unroll
    for (int mi = 0; mi < 3; ++mi) {
        #pragma unroll
        for (int r = 0; r < 4; ++r) {
            int c = wave * 48 + mi * 16 + quad * 4 + r;
            float pb = p2b[c];
            int p = c >> 1;
            if ((r & 1) == 0) {
                #pragma unroll
                for (int ni = 0; ni < 4; ++ni) {
                    if (!okv[ni]) continue;
                    float v = acc2[mi][ni][r] + pb;
                    out[((size_t)bqv[ni] * PP + p) * NN + ndv[ni]] = v;
                }
            } else {
                #pragma unroll
                for (int ni = 0; ni < 4; ++ni) {
                    if (!okv[ni]) continue;
                    float v = acc2[mi][ni][r] + pb;
                    out[BPN + 1 + ((size_t)bqv[ni] * PP + p) * NN + ndv[ni]] = softplus_f(v) + 1e-6f;
                }
            }
        }
    }
}

__global__ void loss_write_kernel(const float* __restrict__ loss, float* __restrict__ out)
{
    if (threadIdx.x == 0) out[BPN] = loss[0];
}

extern "C" void kernel_launch(void* const* d_in, const int* in_sizes, int n_in,
                              void* d_out, int out_size, void* d_ws, size_t ws_size,
                              hipStream_t stream)
{
    const float* x     = (const float*)d_in[0];
    const float* noise = (const float*)d_in[1];
    const float* wg    = (const float*)d_in[2];
    const float* wn    = (const float*)d_in[3];
    const float* W1    = (const float*)d_in[4];
    const float* b1    = (const float*)d_in[5];
    const float* W2    = (const float*)d_in[6];
    const float* b2    = (const float*)d_in[7];
    const float* p1w   = (const float*)d_in[8];
    const float* p1b   = (const float*)d_in[9];
    const float* p2w   = (const float*)d_in[10];
    const float* p2b   = (const float*)d_in[11];
    float* out = (float*)d_out;

    float* ws   = (float*)d_ws;
    float* T    = ws;                          // STOT fp32 (stride LL)
    float* G8   = T + STOT;                    // 8*BB*LL
    float* G    = G8 + 8 * BB * LL;            // BB*LL
    float* LOSS = G + BB * LL;                 // 8
    float* GV   = LOSS + 8;                    // 64
    int*   IDX  = (int*)(GV + 64);             // 64
    float* MU   = (float*)(IDX + 64);          // BB*NN
    float* IV   = MU + MROWS;                  // BB*NN
    short* W1t  = (short*)(IV + MROWS);        // NLAYERS*EE*DHID*LP bf16 [le][d][k]
    short* W2t  = W1t + (size_t)NLAYERS * EE * DHID * LP;  // NLAYERS*EE*LL*DHID
    short* p1wb = W2t + (size_t)NLAYERS * EE * LL * DHID;  // 96*336
    short* p2wb = p1wb + PP * LL;              // 192*96
    short* Tb16 = p2wb + 2 * PP * PP;          // (MROWS + 64 slack) x LP bf16 mirror of T

    revin_stats<<<dim3(BB, 6), 256, 0, stream>>>(x, MU, IV, LOSS);
    revin_tn<<<dim3(BB, 6, 7), 256, 0, stream>>>(x, MU, IV, T, Tb16);

    pcvt_kernel<<<(PP * LL + 2 * PP * PP + 255) / 256, 256, 0, stream>>>(p1w, p2w, p1wb, p2wb);
    wtrans_kernel<<<dim3(8, 6, NLAYERS * EE), 256, 0, stream>>>(W1, W1t, LL, DHID, LP);
    wtrans_kernel<<<dim3(6, 8, NLAYERS * EE), 256, 0, stream>>>(W2, W2t, DHID, LL, DHID);

    // layer-0 gate sums
    gmean_part<<<dim3(BB, 8), 384, 0, stream>>>(T, G8);
    gmean_red<<<BB, 384, 0, stream>>>(G8, G);

    for (int l = 0; l < NLAYERS; ++l) {
        gating_kernel<<<1, 512, 0, stream>>>(G, wg + (size_t)l * LL * EE, wn + (size_t)l * LL * EE,
                                             noise + (size_t)l * BB * EE, IDX, GV, LOSS);
        fc_fused<<<dim3(11, 64), 256, 0, stream>>>(
            Tb16, W1t + (size_t)l * EE * DHID * LP, b1 + (size_t)l * EE * DHID,
            W2t + (size_t)l * EE * LL * DHID, b2 + (size_t)l * EE * LL, IDX, GV, T);
        t2b16_kernel<<<dim3(11, BB), 256, 0, stream>>>(T, Tb16, G);
    }
    proj_fused<<<161, 256, 0, stream>>>(Tb16, p1wb, p1b, p2wb, p2b, out);
    loss_write_kernel<<<1, 64, 0, stream>>>(LOSS, out);
}

// Round 10
// 507.863 us; speedup vs baseline: 1.1483x; 1.1483x over previous
//
#include <hip/hip_runtime.h>
#include <hip/hip_bf16.h>

#define NLAYERS 3
#define BB 32
#define LL 336
#define LP 352                 // K-padded stride for Tb16 / W1t (zeros in pad)
#define NN 321
#define EE 4
#define DHID 512
#define PP 96
#define STOT (BB*NN*LL)        // 3451392
#define MROWS (BB*NN)          // 10272
#define BPN ((size_t)BB*PP*NN) // 986112

typedef __attribute__((ext_vector_type(8))) short short8;
typedef __attribute__((ext_vector_type(4))) float float4v;

union BF { __hip_bfloat16 h; short s; };

__device__ __forceinline__ short f2b(float f) { BF u; u.h = __float2bfloat16(f); return u.s; }

__device__ __forceinline__ float fast_tanh(float y) {
    float e = __expf(2.0f * y);
    return 1.0f - 2.0f / (e + 1.0f);   // exact limits at +-inf
}
__device__ __forceinline__ float gelu_f(float x) {
    return 0.5f * x * (1.0f + fast_tanh(0.7978845608028654f * (x + 0.044715f * x * x * x)));
}
__device__ __forceinline__ float softplus_f(float x) {
    return fmaxf(x, 0.0f) + log1pf(expf(-fabsf(x)));
}

// ---------------- RevIN stats: mu/inv per (b,n); also zeros loss ----------------
__global__ __launch_bounds__(256) void revin_stats(
    const float* __restrict__ x, float* __restrict__ MU, float* __restrict__ IV,
    float* __restrict__ loss)
{
    int b = blockIdx.x, nt = blockIdx.y;
    int tid = threadIdx.x;
    if (b == 0 && nt == 0 && tid == 0) loss[0] = 0.0f;
    int ni = tid & 63, lc = tid >> 6;
    int n = nt * 64 + ni;
    float s = 0.f, ss = 0.f;
    if (n < NN) {
        const float* xp = x + ((size_t)b * LL + lc * 84) * NN + n;
        for (int l = 0; l < 84; ++l, xp += NN) {
            float v = *xp; s += v; ss = fmaf(v, v, ss);
        }
    }
    __shared__ float Ss[4][64], Sq[4][64];
    Ss[lc][ni] = s; Sq[lc][ni] = ss;
    __syncthreads();
    if (lc == 0 && n < NN) {
        float st = ((Ss[0][ni] + Ss[1][ni]) + Ss[2][ni]) + Ss[3][ni];
        float sq = ((Sq[0][ni] + Sq[1][ni]) + Sq[2][ni]) + Sq[3][ni];
        float mu  = st * (1.0f / LL);
        float var = sq * (1.0f / LL) - mu * mu;   // ddof=0
        float inv = 1.0f / sqrtf(var + 1e-5f);
        MU[b * NN + n] = mu;
        IV[b * NN + n] = inv;
    }
}

// ---------------- RevIN transpose+normalize: T (stride LL) + Tb16 (stride LP) ----------------
__global__ __launch_bounds__(256) void revin_tn(
    const float* __restrict__ x, const float* __restrict__ MU, const float* __restrict__ IV,
    float* __restrict__ T, short* __restrict__ Tb16)
{
    int b = blockIdx.x, nt = blockIdx.y, lt = blockIdx.z;
    int n0 = nt * 64, l0 = lt * 48;
    __shared__ float Ls[48][65];
    int tid = threadIdx.x;
    #pragma unroll
    for (int i = 0; i < 12; ++i) {
        int lin = tid + i * 256;
        int li = lin >> 6, ni = lin & 63;
        int n = n0 + ni;
        Ls[li][ni] = (n < NN) ? x[((size_t)b * LL + l0 + li) * NN + n] : 0.f;
    }
    __syncthreads();
    int r = tid >> 2, q = tid & 3;
    int n = n0 + r;
    if (n >= NN) return;
    float mu = MU[b * NN + n], iv = IV[b * NN + n];
    size_t rowf = (size_t)(b * NN + n) * LL + l0;
    size_t rowb = (size_t)(b * NN + n) * LP + l0;
    #pragma unroll
    for (int k = 0; k < 3; ++k) {
        int c = (q + 4 * k) * 4;
        float4 v;
        v.x = (Ls[c    ][r] - mu) * iv;
        v.y = (Ls[c + 1][r] - mu) * iv;
        v.z = (Ls[c + 2][r] - mu) * iv;
        v.w = (Ls[c + 3][r] - mu) * iv;
        *(float4*)&T[rowf + c] = v;
        union { short s[4]; uint2 u; } pk;
        pk.s[0] = f2b(v.x); pk.s[1] = f2b(v.y); pk.s[2] = f2b(v.z); pk.s[3] = f2b(v.w);
        *(uint2*)&Tb16[rowb + c] = pk.u;
    }
    if (lt == 6 && q == 3) {   // zero the K-pad cols 336..352
        size_t base = (size_t)(b * NN + n) * LP;
        *(uint4*)&Tb16[base + 336] = make_uint4(0, 0, 0, 0);
        *(uint4*)&Tb16[base + 344] = make_uint4(0, 0, 0, 0);
    }
}

// ---------------- tiled transpose+convert: dst[d][k(KS-strided)] <- bf16(src[k][d]) ----------------
__global__ __launch_bounds__(256) void wtrans_kernel(
    const float* __restrict__ src0, short* __restrict__ dst0, int K, int D, int KS)
{
    int le = blockIdx.z;
    const float* src = src0 + (size_t)le * K * D;
    short* dst = dst0 + (size_t)le * D * KS;
    int d0 = blockIdx.x * 64, k0 = blockIdx.y * 64;
    __shared__ short Ws[64][72];
    int tid = threadIdx.x;
    #pragma unroll
    for (int i = 0; i < 16; ++i) {
        int lin = tid + i * 256;
        int ki = lin >> 6, dj = lin & 63;
        int k = k0 + ki, d = d0 + dj;
        Ws[ki][dj] = (k < K && d < D) ? f2b(src[(size_t)k * D + d]) : (short)0;
    }
    __syncthreads();
    int di = tid >> 2, d = d0 + di;
    if (d >= D) return;
    #pragma unroll
    for (int kp = 0; kp < 2; ++kp) {
        int kj = ((tid & 3) + 4 * kp) * 8;
        if (k0 + kj >= KS) continue;
        union { short s[8]; uint4 u; } pk;
        #pragma unroll
        for (int j = 0; j < 8; ++j) pk.s[j] = Ws[kj + j][di];
        *(uint4*)(dst + (size_t)d * KS + k0 + kj) = pk.u;
    }
}

// ---------------- small convert for p1w/p2w (already [n][k]) ----------------
__global__ __launch_bounds__(256) void pcvt_kernel(
    const float* __restrict__ p1w, const float* __restrict__ p2w,
    short* __restrict__ p1wb, short* __restrict__ p2wb)
{
    int i = blockIdx.x * 256 + threadIdx.x;
    if (i < PP * LL) p1wb[i] = f2b(p1w[i]);
    else if (i < PP * LL + 2 * PP * PP) { int j = i - PP * LL; p2wb[j] = f2b(p2w[j]); }
}

// ---------------- gate features (layer 0 only): 8-way partial sums over n ----------------
__global__ __launch_bounds__(384) void gmean_part(
    const float* __restrict__ T, float* __restrict__ G8)
{
    int b = blockIdx.x, c = blockIdx.y;
    int l = threadIdx.x;
    if (l >= LL) return;
    int n_lo = c * 41, n_hi = (NN < n_lo + 41) ? NN : (n_lo + 41);
    const float* tp = T + ((size_t)b * NN + n_lo) * LL + l;
    float s = 0.f;
    for (int n = n_lo; n < n_hi; ++n, tp += LL) s += *tp;
    G8[((size_t)c * BB + b) * LL + l] = s;
}

__global__ __launch_bounds__(384) void gmean_red(
    const float* __restrict__ G8, float* __restrict__ G)
{
    int b = blockIdx.x;
    int l = threadIdx.x;
    if (l >= LL) return;
    float s = 0.f;
    #pragma unroll
    for (int c = 0; c < 8; ++c) s += G8[((size_t)c * BB + b) * LL + l];
    G[b * LL + l] = s;     // SUM (gating applies 1/NN)
}

// ---------------- noisy top-k gating + aux loss; G holds SUMS; zeroes G at end ----------------
__global__ __launch_bounds__(512) void gating_kernel(
    float* __restrict__ G, const float* __restrict__ wg,
    const float* __restrict__ wn, const float* __restrict__ noise,
    int* __restrict__ IDX, float* __restrict__ GV, float* __restrict__ loss)
{
    __shared__ float pc[BB][EE][4], pn[BB][EE][4];
    __shared__ float s_clean[BB][EE], s_nstd[BB][EE], s_noisy[BB][EE], s_gates[BB][EE];
    __shared__ float s_thr_in[BB], s_thr_out[BB];
    __shared__ float s_imp[EE], s_load[EE];
    int tid = threadIdx.x;
    {
        int b = tid >> 4, e = (tid >> 2) & 3, sub = tid & 3;
        float c = 0.f, nr = 0.f;
        const float* gp = G + b * LL;
        for (int l = sub * 84; l < sub * 84 + 84; ++l) {
            float gv = gp[l] * (1.0f / NN);
            c  = fmaf(gv, wg[l * EE + e], c);
            nr = fmaf(gv, wn[l * EE + e], nr);
        }
        pc[b][e][sub] = c; pn[b][e][sub] = nr;
    }
    __syncthreads();
    // all G reads done; zero G for next layer's accumulation
    for (int i2 = tid; i2 < BB * LL; i2 += 512) G[i2] = 0.0f;
    int b = tid >> 2, e = tid & 3;   // valid for tid < 128
    if (tid < 128) {
        float c  = ((pc[b][e][0] + pc[b][e][1]) + pc[b][e][2]) + pc[b][e][3];
        float nr = ((pn[b][e][0] + pn[b][e][1]) + pn[b][e][2]) + pn[b][e][3];
        float nstd  = softplus_f(nr) + 1e-2f;
        float noisy = fmaf(noise[b * EE + e], nstd, c);
        s_clean[b][e] = c; s_nstd[b][e] = nstd; s_noisy[b][e] = noisy;
    }
    __syncthreads();
    if (tid < 128 && e == 0) {
        float v[4];
        #pragma unroll
        for (int i = 0; i < 4; ++i) v[i] = s_noisy[b][i];
        int i0 = 0;
        for (int i = 1; i < 4; ++i) if (v[i] > v[i0]) i0 = i;
        int i1 = -1;
        for (int i = 0; i < 4; ++i) { if (i == i0) continue; if (i1 < 0 || v[i] > v[i1]) i1 = i; }
        float m3 = -1e30f;
        for (int i = 0; i < 4; ++i) { if (i == i0 || i == i1) continue; if (v[i] > m3) m3 = v[i]; }
        float e1  = expf(v[i1] - v[i0]);
        float invd = 1.0f / (1.0f + e1);
        #pragma unroll
        for (int i = 0; i < 4; ++i) s_gates[b][i] = 0.f;
        s_gates[b][i0] = invd;
        s_gates[b][i1] = e1 * invd;
        s_thr_in[b]  = m3;       // (k+1)-th value
        s_thr_out[b] = v[i1];    // k-th value
        IDX[2*b] = i0; IDX[2*b+1] = i1;
        GV[2*b] = invd; GV[2*b+1] = e1 * invd;
    }
    __syncthreads();
    if (tid < EE) {
        int ee = tid;
        float imp = 0.f, ld = 0.f;
        for (int bb2 = 0; bb2 < BB; ++bb2) {
            imp += s_gates[bb2][ee];
            float thr = (s_noisy[bb2][ee] > s_thr_in[bb2]) ? s_thr_in[bb2] : s_thr_out[bb2];
            float z = (s_clean[bb2][ee] - thr) / s_nstd[bb2][ee];
            ld += 0.5f * (1.0f + erff(z * 0.7071067811865476f));
        }
        s_imp[ee] = imp; s_load[ee] = ld;
    }
    __syncthreads();
    if (tid == 0) {
        float aux = 0.f;
        {
            float m = (s_imp[0] + s_imp[1] + s_imp[2] + s_imp[3]) * 0.25f;
            float var = 0.f;
            for (int i = 0; i < 4; ++i) { float d = s_imp[i] - m; var += d * d; }
            var *= (1.0f / 3.0f);
            aux += var / (m * m + 1e-10f);
        }
        {
            float m = (s_load[0] + s_load[1] + s_load[2] + s_load[3]) * 0.25f;
            float var = 0.f;
            for (int i = 0; i < 4; ++i) { float d = s_load[i] - m; var += d * d; }
            var *= (1.0f / 3.0f);
            aux += var / (m * m + 1e-10f);
        }
        loss[0] += 0.01f * aux;
    }
}

// ---------------- FC1 (MFMA): A in LDS (full K, 1 barrier), B direct-global ----------------
// grid (4, 6, 64): x = d-tile(128), y = m-tile(64), z = b*2+slot
__global__ __launch_bounds__(256, 3) void fc1_mfma(
    const short* __restrict__ Tb16, const short* __restrict__ W1t_l,
    const float* __restrict__ b1_l, const int* __restrict__ IDX,
    const float* __restrict__ GV, short* __restrict__ Hs)
{
    int z = blockIdx.z;
    int b = z >> 1;
    int e = IDX[z];
    float g = GV[z];
    int m0 = blockIdx.y * 64, n0 = blockIdx.x * 128;
    int tid = threadIdx.x;
    int wave = tid >> 6, lane = tid & 63, quad = lane >> 4, l16 = lane & 15;
    int wn = wave * 32;
    __shared__ short Al[64][360];   // stride 360 shorts = 720B -> ~2-way banks
    {   // stage full 64 x 352 A tile once
        int r = tid >> 2, c0 = (tid & 3) * 8;
        const short* src = Tb16 + ((size_t)b * NN + m0 + r) * LP + c0;
        #pragma unroll
        for (int ks = 0; ks < 11; ++ks)
            *(uint4*)&Al[r][c0 + ks * 32] = *(const uint4*)(src + ks * 32);
    }
    __syncthreads();

    const short* Bb = W1t_l + ((size_t)e * DHID + n0 + wn + l16) * LP + quad * 8;
    float4v zero4 = {0.f, 0.f, 0.f, 0.f};
    float4v acc[4][2];
    #pragma unroll
    for (int i = 0; i < 4; ++i)
        #pragma unroll
        for (int j = 0; j < 2; ++j) acc[i][j] = zero4;

    #pragma unroll
    for (int ks = 0; ks < 11; ++ks) {   // barrier-free: B loads pipeline freely
        int off = ks * 32;
        short8 bf0 = *(const short8*)(Bb + off);
        short8 bf1 = *(const short8*)(Bb + (size_t)16 * LP + off);
        short8 af[4];
        #pragma unroll
        for (int mi = 0; mi < 4; ++mi) af[mi] = *(const short8*)&Al[mi * 16 + l16][off + quad * 8];
        #pragma unroll
        for (int mi = 0; mi < 4; ++mi) {
            acc[mi][0] = __builtin_amdgcn_mfma_f32_16x16x32_bf16(af[mi], bf0, acc[mi][0], 0, 0, 0);
            acc[mi][1] = __builtin_amdgcn_mfma_f32_16x16x32_bf16(af[mi], bf1, acc[mi][1], 0, 0, 0);
        }
    }
    const float* bb = b1_l + (size_t)e * DHID;
    float bias[2];
    #pragma unroll
    for (int ni = 0; ni < 2; ++ni) bias[ni] = bb[n0 + wn + ni * 16 + l16];
    short* Ho = Hs + (size_t)z * NN * DHID;
    #pragma unroll
    for (int mi = 0; mi < 4; ++mi) {
        #pragma unroll
        for (int r = 0; r < 4; ++r) {
            int gm = m0 + mi * 16 + quad * 4 + r;   // C/D: col=lane&15, row=quad*4+reg
            if (gm >= NN) continue;
            #pragma unroll
            for (int ni = 0; ni < 2; ++ni) {
                int gd = n0 + wn + ni * 16 + l16;
                float v = acc[mi][ni][r] + bias[ni];
                Ho[(size_t)gm * DHID + gd] = f2b(g * gelu_f(v));
            }
        }
    }
}

// ---------------- FC2 (MFMA, slot-split): T += atomically Hs[z]@W2[e] + g*b2 ----------------
// grid (3, 6, 64): x = l-tile(128), y = m-tile(64), z = b*2+slot. K = 512 per block.
__global__ __launch_bounds__(256, 3) void fc2_mfma(
    const short* __restrict__ Hs, const short* __restrict__ W2t_l,
    const float* __restrict__ b2_l, float* __restrict__ T,
    const int* __restrict__ IDX, const float* __restrict__ GV)
{
    int z = blockIdx.z;
    int b = z >> 1;
    int e = IDX[z];
    float g = GV[z];
    int m0 = blockIdx.y * 64, n0 = blockIdx.x * 128;
    int tid = threadIdx.x;
    int wave = tid >> 6, lane = tid & 63, quad = lane >> 4, l16 = lane & 15;
    int wn = wave * 32;
    __shared__ short Al[64][264];   // stride 264 shorts = 528B -> 2-way frag reads
    float4v zero4 = {0.f, 0.f, 0.f, 0.f};
    float4v acc[4][2];
    #pragma unroll
    for (int i = 0; i < 4; ++i)
        #pragma unroll
        for (int j = 0; j < 2; ++j) acc[i][j] = zero4;

    int r8 = tid >> 5, c0s = (tid & 31) * 8;
    #pragma unroll
    for (int chunk = 0; chunk < 2; ++chunk) {   // K chunks of 256
        int koff = chunk * 256;
        const short* As = Hs + ((size_t)z * NN + m0) * DHID + koff;
        #pragma unroll
        for (int i = 0; i < 8; ++i)
            *(uint4*)&Al[i * 8 + r8][c0s] = *(const uint4*)(As + (size_t)(i * 8 + r8) * DHID + c0s);
        __syncthreads();
        const short* Bb = W2t_l + ((size_t)e * LL + n0 + wn + l16) * DHID + koff + quad * 8;
        #pragma unroll
        for (int ks = 0; ks < 8; ++ks) {
            int off = ks * 32;
            short8 bf0 = *(const short8*)(Bb + off);
            short8 bf1 = *(const short8*)(Bb + (size_t)16 * DHID + off);
            short8 af[4];
            #pragma unroll
            for (int mi = 0; mi < 4; ++mi) af[mi] = *(const short8*)&Al[mi * 16 + l16][off + quad * 8];
            #pragma unroll
            for (int mi = 0; mi < 4; ++mi) {
                acc[mi][0] = __builtin_amdgcn_mfma_f32_16x16x32_bf16(af[mi], bf0, acc[mi][0], 0, 0, 0);
                acc[mi][1] = __builtin_amdgcn_mfma_f32_16x16x32_bf16(af[mi], bf1, acc[mi][1], 0, 0, 0);
            }
        }
        __syncthreads();
    }
    const float* b2e = b2_l + (size_t)e * LL;
    float bias[2]; int glc[2];
    #pragma unroll
    for (int ni = 0; ni < 2; ++ni) {
        int gl = n0 + wn + ni * 16 + l16;
        glc[ni] = gl;
        bias[ni] = (gl < LL) ? (g * b2e[gl]) : 0.f;
    }
    float* Tb = T + (size_t)b * NN * LL;
    #pragma unroll
    for (int mi = 0; mi < 4; ++mi) {
        #pragma unroll
        for (int r = 0; r < 4; ++r) {
            int gm = m0 + mi * 16 + quad * 4 + r;
            if (gm >= NN) continue;
            #pragma unroll
            for (int ni = 0; ni < 2; ++ni) {
                if (glc[ni] < LL)
                    unsafeAtomicAdd(&Tb[(size_t)gm * LL + glc[ni]], acc[mi][ni][r] + bias[ni]);
            }
        }
    }
}

// ---------------- T -> Tb16 mirror refresh + gate-sum accumulation for next layer ----------------
// grid (11, 32): x = m-tile(32), y = b
__global__ __launch_bounds__(256) void t2b16_kernel(
    const float* __restrict__ T, short* __restrict__ Tb16, float* __restrict__ G)
{
    int mt = blockIdx.x, b = blockIdx.y;
    int m0 = mt * 32;
    int tid = threadIdx.x;
    #pragma unroll
    for (int i = 0; i < 11; ++i) {
        int idx = tid + i * 256;
        if (idx < 2688) {
            int r = idx / 84, cq = (idx - r * 84) * 4;
            int gm = m0 + r;
            if (gm < NN) {
                float4 v = *(const float4*)&T[(size_t)(b * NN + gm) * LL + cq];
                union { short s[4]; uint2 u; } pk;
                pk.s[0] = f2b(v.x); pk.s[1] = f2b(v.y); pk.s[2] = f2b(v.z); pk.s[3] = f2b(v.w);
                *(uint2*)&Tb16[(size_t)(b * NN + gm) * LP + cq] = pk.u;
            }
        }
    }
    if (tid < 64) {   // zero K-pad cols 336..352
        int r = tid >> 1, gm = m0 + r;
        if (gm < NN)
            *(uint4*)&Tb16[(size_t)(b * NN + gm) * LP + 336 + (tid & 1) * 8] = make_uint4(0, 0, 0, 0);
    }
    if (tid < 84) {   // column partial sums over this block's rows -> G (zeroed by gating)
        int rmax = NN - m0; if (rmax > 32) rmax = 32;
        float4 s = make_float4(0.f, 0.f, 0.f, 0.f);
        const float* tp = T + (size_t)(b * NN + m0) * LL + tid * 4;
        for (int r = 0; r < rmax; ++r, tp += LL) {
            float4 v = *(const float4*)tp;
            s.x += v.x; s.y += v.y; s.z += v.z; s.w += v.w;
        }
        float* gp = G + b * LL + tid * 4;
        unsafeAtomicAdd(gp + 0, s.x);
        unsafeAtomicAdd(gp + 1, s.y);
        unsafeAtomicAdd(gp + 2, s.z);
        unsafeAtomicAdd(gp + 3, s.w);
    }
}

// ---------------- fused projection head (MFMA), transposed phase 2 ----------------
__global__ __launch_bounds__(256) void proj_fused(
    const short* __restrict__ Tb16,
    const short* __restrict__ p1wb, const float* __restrict__ p1b,
    const short* __restrict__ p2wb, const float* __restrict__ p2b,
    float* __restrict__ out)
{
    __shared__ short smem[26624];                       // 52 KB, manually carved
    short (*Al)[40]   = (short (*)[40])smem;            // 64x40   (phase 1)
    short (*Bl1)[40]  = (short (*)[40])(smem + 2560);   // 96x40   (phase 1)
    short (*B2)[104]  = (short (*)[104])smem;           // 192x104 (phase 2, overlays Al/Bl1)
    short (*Hp)[104]  = (short (*)[104])(smem + 19968); // 64x104

    int m0 = blockIdx.x * 64;
    int tid = threadIdx.x;
    int wave = tid >> 6, lane = tid & 63, quad = lane >> 4, l16 = lane & 15;
    float4v zero4 = {0.f, 0.f, 0.f, 0.f};

    // ---- phase 1: 64 x 96 = T-tile @ p1w^T ----
    float4v acc1[6];
    #pragma unroll
    for (int i = 0; i < 6; ++i) acc1[i] = zero4;
    int am = tid >> 2, ako = (tid & 3) * 8;
    for (int k0 = 0; k0 < LL; k0 += 32) {
        {
            int gm = m0 + am;
            uint4 val = make_uint4(0, 0, 0, 0);
            if (gm < MROWS) val = *(const uint4*)(Tb16 + (size_t)gm * LP + k0 + ako);
            *(uint4*)&Al[am][ako] = val;
        }
        #pragma unroll
        for (int uu = 0; uu < 2; ++uu) {
            int u = tid + uu * 256;
            if (u < 384) {
                int n = u >> 2, ko = (u & 3) * 8;
                int gk = k0 + ko;
                uint4 val = make_uint4(0, 0, 0, 0);
                if (gk < LL) val = *(const uint4*)(p1wb + (size_t)n * LL + gk);
                *(uint4*)&Bl1[n][ko] = val;
            }
        }
        __syncthreads();
        short8 af = *(const short8*)&Al[wave * 16 + l16][quad * 8];
        #pragma unroll
        for (int ni = 0; ni < 6; ++ni) {
            short8 bfv = *(const short8*)&Bl1[ni * 16 + l16][quad * 8];
            acc1[ni] = __builtin_amdgcn_mfma_f32_16x16x32_bf16(af, bfv, acc1[ni], 0, 0, 0);
        }
        __syncthreads();
    }
    #pragma unroll
    for (int ni = 0; ni < 6; ++ni) {
        #pragma unroll
        for (int r = 0; r < 4; ++r) {
            int ml = wave * 16 + quad * 4 + r;
            int p = ni * 16 + l16;
            Hp[ml][p] = f2b(fast_tanh(acc1[ni][r] + p1b[p]));
        }
    }
    for (int u = tid; u < 192 * 12; u += 256) {
        int n = u / 12, ko = (u - n * 12) * 8;
        *(uint4*)&B2[n][ko] = *(const uint4*)(p2wb + (size_t)n * PP + ko);
    }
    __syncthreads();

    // ---- phase 2 (transposed): rows = c (192), cols = node (64), K = 96 ----
    float4v acc2[3][4];
    #pragma unroll
    for (int i = 0; i < 3; ++i)
        #pragma unroll
        for (int j = 0; j < 4; ++j) acc2[i][j] = zero4;
    #pragma unroll
    for (int kc = 0; kc < 3; ++kc) {
        int k0 = kc * 32 + quad * 8;
        short8 af[3], bfv[4];
        #pragma unroll
        for (int mi = 0; mi < 3; ++mi) af[mi] = *(const short8*)&B2[wave * 48 + mi * 16 + l16][k0];
        #pragma unroll
        for (int ni = 0; ni < 4; ++ni) bfv[ni] = *(const short8*)&Hp[ni * 16 + l16][k0];
        #pragma unroll
        for (int mi = 0; mi < 3; ++mi)
            #pragma unroll
            for (int ni = 0; ni < 4; ++ni)
                acc2[mi][ni] = __builtin_amdgcn_mfma_f32_16x16x32_bf16(af[mi], bfv[ni], acc2[mi][ni], 0, 0, 0);
    }
    int bqv[4], ndv[4]; bool okv[4];
    #pragma unroll
    for (int ni = 0; ni < 4; ++ni) {
        int gm = m0 + ni * 16 + l16;
        okv[ni] = (gm < MROWS);
        int bq = gm / NN;
        bqv[ni] = bq; ndv[ni] = gm - bq * NN;
    }
    #pragma unroll
    for (int mi = 0; mi < 3; ++mi) {
        #pragma unroll
        for (int r = 0; r < 4; ++r) {
            int c = wave * 48 + mi * 16 + quad * 4 + r;
            float pb = p2b[c];
            int p = c >> 1;
            if ((r & 1) == 0) {
                #pragma unroll
                for (int ni = 0; ni < 4; ++ni) {
                    if (!okv[ni]) continue;
                    float v = acc2[mi][ni][r] + pb;
                    out[((size_t)bqv[ni] * PP + p) * NN + ndv[ni]] = v;
                }
            } else {
                #pragma unroll
                for (int ni = 0; ni < 4; ++ni) {
                    if (!okv[ni]) continue;
                    float v = acc2[mi][ni][r] + pb;
                    out[BPN + 1 + ((size_t)bqv[ni] * PP + p) * NN + ndv[ni]] = softplus_f(v) + 1e-6f;
                }
            }
        }
    }
}

__global__ void loss_write_kernel(const float* __restrict__ loss, float* __restrict__ out)
{
    if (threadIdx.x == 0) out[BPN] = loss[0];
}

extern "C" void kernel_launch(void* const* d_in, const int* in_sizes, int n_in,
                              void* d_out, int out_size, void* d_ws, size_t ws_size,
                              hipStream_t stream)
{
    const float* x     = (const float*)d_in[0];
    const float* noise = (const float*)d_in[1];
    const float* wg    = (const float*)d_in[2];
    const float* wn    = (const float*)d_in[3];
    const float* W1    = (const float*)d_in[4];
    const float* b1    = (const float*)d_in[5];
    const float* W2    = (const float*)d_in[6];
    const float* b2    = (const float*)d_in[7];
    const float* p1w   = (const float*)d_in[8];
    const float* p1b   = (const float*)d_in[9];
    const float* p2w   = (const float*)d_in[10];
    const float* p2b   = (const float*)d_in[11];
    float* out = (float*)d_out;

    float* ws   = (float*)d_ws;
    float* T    = ws;                          // STOT fp32 (stride LL)
    float* G8   = T + STOT;                    // 8*BB*LL
    float* G    = G8 + 8 * BB * LL;            // BB*LL
    float* LOSS = G + BB * LL;                 // 8
    float* GV   = LOSS + 8;                    // 64
    int*   IDX  = (int*)(GV + 64);             // 64
    float* MU   = (float*)(IDX + 64);          // BB*NN
    float* IV   = MU + MROWS;                  // BB*NN
    short* W1t  = (short*)(IV + MROWS);        // NLAYERS*EE*DHID*LP bf16 [le][d][k]
    short* W2t  = W1t + (size_t)NLAYERS * EE * DHID * LP;  // NLAYERS*EE*LL*DHID
    short* p1wb = W2t + (size_t)NLAYERS * EE * LL * DHID;  // 96*336
    short* p2wb = p1wb + PP * LL;              // 192*96
    short* Tb16 = p2wb + 2 * PP * PP;          // (MROWS + slack) x LP bf16 mirror of T
    short* Hs   = Tb16 + (size_t)(MROWS + 64) * LP;  // 64*NN rows + slack x DHID bf16

    revin_stats<<<dim3(BB, 6), 256, 0, stream>>>(x, MU, IV, LOSS);
    revin_tn<<<dim3(BB, 6, 7), 256, 0, stream>>>(x, MU, IV, T, Tb16);

    pcvt_kernel<<<(PP * LL + 2 * PP * PP + 255) / 256, 256, 0, stream>>>(p1w, p2w, p1wb, p2wb);
    wtrans_kernel<<<dim3(8, 6, NLAYERS * EE), 256, 0, stream>>>(W1, W1t, LL, DHID, LP);
    wtrans_kernel<<<dim3(6, 8, NLAYERS * EE), 256, 0, stream>>>(W2, W2t, DHID, LL, DHID);

    // layer-0 gate sums
    gmean_part<<<dim3(BB, 8), 384, 0, stream>>>(T, G8);
    gmean_red<<<BB, 384, 0, stream>>>(G8, G);

    for (int l = 0; l < NLAYERS; ++l) {
        gating_kernel<<<1, 512, 0, stream>>>(G, wg + (size_t)l * LL * EE, wn + (size_t)l * LL * EE,
                                             noise + (size_t)l * BB * EE, IDX, GV, LOSS);
        fc1_mfma<<<dim3(4, 6, 64), 256, 0, stream>>>(
            Tb16, W1t + (size_t)l * EE * DHID * LP, b1 + (size_t)l * EE * DHID, IDX, GV, Hs);
        fc2_mfma<<<dim3(3, 6, 64), 256, 0, stream>>>(
            Hs, W2t + (size_t)l * EE * LL * DHID, b2 + (size_t)l * EE * LL, T, IDX, GV);
        t2b16_kernel<<<dim3(11, BB), 256, 0, stream>>>(T, Tb16, G);
    }
    proj_fused<<<161, 256, 0, stream>>>(Tb16, p1wb, p1b, p2wb, p2b, out);
    loss_write_kernel<<<1, 64, 0, stream>>>(LOSS, out);
}

// Round 11
// 443.918 us; speedup vs baseline: 1.3137x; 1.1440x over previous
//
#include <hip/hip_runtime.h>
#include <hip/hip_bf16.h>

#define NLAYERS 3
#define BB 32
#define LL 336
#define LP 352                 // K-padded stride for Tb16 / W1t / p1wb (zeros in pad)
#define NN 321
#define EE 4
#define DHID 512
#define PP 96
#define STOT (BB*NN*LL)        // 3451392
#define MROWS (BB*NN)          // 10272
#define BPN ((size_t)BB*PP*NN) // 986112

typedef __attribute__((ext_vector_type(8))) short short8;
typedef __attribute__((ext_vector_type(4))) float float4v;

union BF { __hip_bfloat16 h; short s; };

__device__ __forceinline__ short f2b(float f) { BF u; u.h = __float2bfloat16(f); return u.s; }

__device__ __forceinline__ float fast_tanh(float y) {
    float e = __expf(2.0f * y);
    return 1.0f - 2.0f / (e + 1.0f);   // exact limits at +-inf
}
__device__ __forceinline__ float gelu_f(float x) {
    return 0.5f * x * (1.0f + fast_tanh(0.7978845608028654f * (x + 0.044715f * x * x * x)));
}
__device__ __forceinline__ float softplus_f(float x) {
    return fmaxf(x, 0.0f) + log1pf(expf(-fabsf(x)));
}

// ---------------- RevIN stats: mu/inv per (b,n); also zeros loss ----------------
__global__ __launch_bounds__(256) void revin_stats(
    const float* __restrict__ x, float* __restrict__ MU, float* __restrict__ IV,
    float* __restrict__ loss)
{
    int b = blockIdx.x, nt = blockIdx.y;
    int tid = threadIdx.x;
    if (b == 0 && nt == 0 && tid == 0) loss[0] = 0.0f;
    int ni = tid & 63, lc = tid >> 6;
    int n = nt * 64 + ni;
    float s = 0.f, ss = 0.f;
    if (n < NN) {
        const float* xp = x + ((size_t)b * LL + lc * 84) * NN + n;
        for (int l = 0; l < 84; ++l, xp += NN) {
            float v = *xp; s += v; ss = fmaf(v, v, ss);
        }
    }
    __shared__ float Ss[4][64], Sq[4][64];
    Ss[lc][ni] = s; Sq[lc][ni] = ss;
    __syncthreads();
    if (lc == 0 && n < NN) {
        float st = ((Ss[0][ni] + Ss[1][ni]) + Ss[2][ni]) + Ss[3][ni];
        float sq = ((Sq[0][ni] + Sq[1][ni]) + Sq[2][ni]) + Sq[3][ni];
        float mu  = st * (1.0f / LL);
        float var = sq * (1.0f / LL) - mu * mu;   // ddof=0
        float inv = 1.0f / sqrtf(var + 1e-5f);
        MU[b * NN + n] = mu;
        IV[b * NN + n] = inv;
    }
}

// ---------------- RevIN transpose+normalize: T (stride LL) + Tb16 (stride LP) ----------------
__global__ __launch_bounds__(256) void revin_tn(
    const float* __restrict__ x, const float* __restrict__ MU, const float* __restrict__ IV,
    float* __restrict__ T, short* __restrict__ Tb16)
{
    int b = blockIdx.x, nt = blockIdx.y, lt = blockIdx.z;
    int n0 = nt * 64, l0 = lt * 48;
    __shared__ float Ls[48][65];
    int tid = threadIdx.x;
    #pragma unroll
    for (int i = 0; i < 12; ++i) {
        int lin = tid + i * 256;
        int li = lin >> 6, ni = lin & 63;
        int n = n0 + ni;
        Ls[li][ni] = (n < NN) ? x[((size_t)b * LL + l0 + li) * NN + n] : 0.f;
    }
    __syncthreads();
    int r = tid >> 2, q = tid & 3;
    int n = n0 + r;
    if (n >= NN) return;
    float mu = MU[b * NN + n], iv = IV[b * NN + n];
    size_t rowf = (size_t)(b * NN + n) * LL + l0;
    size_t rowb = (size_t)(b * NN + n) * LP + l0;
    #pragma unroll
    for (int k = 0; k < 3; ++k) {
        int c = (q + 4 * k) * 4;
        float4 v;
        v.x = (Ls[c    ][r] - mu) * iv;
        v.y = (Ls[c + 1][r] - mu) * iv;
        v.z = (Ls[c + 2][r] - mu) * iv;
        v.w = (Ls[c + 3][r] - mu) * iv;
        *(float4*)&T[rowf + c] = v;
        union { short s[4]; uint2 u; } pk;
        pk.s[0] = f2b(v.x); pk.s[1] = f2b(v.y); pk.s[2] = f2b(v.z); pk.s[3] = f2b(v.w);
        *(uint2*)&Tb16[rowb + c] = pk.u;
    }
    if (lt == 6 && q == 3) {   // zero the K-pad cols 336..352
        size_t base = (size_t)(b * NN + n) * LP;
        *(uint4*)&Tb16[base + 336] = make_uint4(0, 0, 0, 0);
        *(uint4*)&Tb16[base + 344] = make_uint4(0, 0, 0, 0);
    }
}

// ---------------- tiled transpose+convert: dst[d][k(KS-strided)] <- bf16(src[k][d]) ----------------
__global__ __launch_bounds__(256) void wtrans_kernel(
    const float* __restrict__ src0, short* __restrict__ dst0, int K, int D, int KS)
{
    int le = blockIdx.z;
    const float* src = src0 + (size_t)le * K * D;
    short* dst = dst0 + (size_t)le * D * KS;
    int d0 = blockIdx.x * 64, k0 = blockIdx.y * 64;
    __shared__ short Ws[64][72];
    int tid = threadIdx.x;
    #pragma unroll
    for (int i = 0; i < 16; ++i) {
        int lin = tid + i * 256;
        int ki = lin >> 6, dj = lin & 63;
        int k = k0 + ki, d = d0 + dj;
        Ws[ki][dj] = (k < K && d < D) ? f2b(src[(size_t)k * D + d]) : (short)0;
    }
    __syncthreads();
    int di = tid >> 2, d = d0 + di;
    if (d >= D) return;
    #pragma unroll
    for (int kp = 0; kp < 2; ++kp) {
        int kj = ((tid & 3) + 4 * kp) * 8;
        if (k0 + kj >= KS) continue;
        union { short s[8]; uint4 u; } pk;
        #pragma unroll
        for (int j = 0; j < 8; ++j) pk.s[j] = Ws[kj + j][di];
        *(uint4*)(dst + (size_t)d * KS + k0 + kj) = pk.u;
    }
}

// ---------------- small convert for p1w (pad to LP) / p2w ----------------
__global__ __launch_bounds__(256) void pcvt_kernel(
    const float* __restrict__ p1w, const float* __restrict__ p2w,
    short* __restrict__ p1wb, short* __restrict__ p2wb)
{
    int i = blockIdx.x * 256 + threadIdx.x;
    if (i < PP * LP) {
        int n = i / LP, k = i - n * LP;
        p1wb[i] = (k < LL) ? f2b(p1w[n * LL + k]) : (short)0;
    } else if (i < PP * LP + 2 * PP * PP) {
        int j = i - PP * LP;
        p2wb[j] = f2b(p2w[j]);
    }
}

// ---------------- gate features (layer 0 only): 8-way partial sums over n ----------------
__global__ __launch_bounds__(384) void gmean_part(
    const float* __restrict__ T, float* __restrict__ G8)
{
    int b = blockIdx.x, c = blockIdx.y;
    int l = threadIdx.x;
    if (l >= LL) return;
    int n_lo = c * 41, n_hi = (NN < n_lo + 41) ? NN : (n_lo + 41);
    const float* tp = T + ((size_t)b * NN + n_lo) * LL + l;
    float s = 0.f;
    for (int n = n_lo; n < n_hi; ++n, tp += LL) s += *tp;
    G8[((size_t)c * BB + b) * LL + l] = s;
}

__global__ __launch_bounds__(384) void gmean_red(
    const float* __restrict__ G8, float* __restrict__ G)
{
    int b = blockIdx.x;
    int l = threadIdx.x;
    if (l >= LL) return;
    float s = 0.f;
    #pragma unroll
    for (int c = 0; c < 8; ++c) s += G8[((size_t)c * BB + b) * LL + l];
    G[b * LL + l] = s;     // SUM (gating applies 1/NN)
}

// ---------------- noisy top-k gating + aux loss; G holds SUMS; zeroes G at end ----------------
__global__ __launch_bounds__(512) void gating_kernel(
    float* __restrict__ G, const float* __restrict__ wg,
    const float* __restrict__ wn, const float* __restrict__ noise,
    int* __restrict__ IDX, float* __restrict__ GV, float* __restrict__ loss)
{
    __shared__ float pc[BB][EE][4], pn[BB][EE][4];
    __shared__ float s_clean[BB][EE], s_nstd[BB][EE], s_noisy[BB][EE], s_gates[BB][EE];
    __shared__ float s_thr_in[BB], s_thr_out[BB];
    __shared__ float s_imp[EE], s_load[EE];
    int tid = threadIdx.x;
    {
        int b = tid >> 4, e = (tid >> 2) & 3, sub = tid & 3;
        float c = 0.f, nr = 0.f;
        const float* gp = G + b * LL;
        for (int l = sub * 84; l < sub * 84 + 84; ++l) {
            float gv = gp[l] * (1.0f / NN);
            c  = fmaf(gv, wg[l * EE + e], c);
            nr = fmaf(gv, wn[l * EE + e], nr);
        }
        pc[b][e][sub] = c; pn[b][e][sub] = nr;
    }
    __syncthreads();
    // all G reads done; zero G for next layer's accumulation
    for (int i2 = tid; i2 < BB * LL; i2 += 512) G[i2] = 0.0f;
    int b = tid >> 2, e = tid & 3;   // valid for tid < 128
    if (tid < 128) {
        float c  = ((pc[b][e][0] + pc[b][e][1]) + pc[b][e][2]) + pc[b][e][3];
        float nr = ((pn[b][e][0] + pn[b][e][1]) + pn[b][e][2]) + pn[b][e][3];
        float nstd  = softplus_f(nr) + 1e-2f;
        float noisy = fmaf(noise[b * EE + e], nstd, c);
        s_clean[b][e] = c; s_nstd[b][e] = nstd; s_noisy[b][e] = noisy;
    }
    __syncthreads();
    if (tid < 128 && e == 0) {
        float v[4];
        #pragma unroll
        for (int i = 0; i < 4; ++i) v[i] = s_noisy[b][i];
        int i0 = 0;
        for (int i = 1; i < 4; ++i) if (v[i] > v[i0]) i0 = i;
        int i1 = -1;
        for (int i = 0; i < 4; ++i) { if (i == i0) continue; if (i1 < 0 || v[i] > v[i1]) i1 = i; }
        float m3 = -1e30f;
        for (int i = 0; i < 4; ++i) { if (i == i0 || i == i1) continue; if (v[i] > m3) m3 = v[i]; }
        float e1  = expf(v[i1] - v[i0]);
        float invd = 1.0f / (1.0f + e1);
        #pragma unroll
        for (int i = 0; i < 4; ++i) s_gates[b][i] = 0.f;
        s_gates[b][i0] = invd;
        s_gates[b][i1] = e1 * invd;
        s_thr_in[b]  = m3;       // (k+1)-th value
        s_thr_out[b] = v[i1];    // k-th value
        IDX[2*b] = i0; IDX[2*b+1] = i1;
        GV[2*b] = invd; GV[2*b+1] = e1 * invd;
    }
    __syncthreads();
    if (tid < EE) {
        int ee = tid;
        float imp = 0.f, ld = 0.f;
        for (int bb2 = 0; bb2 < BB; ++bb2) {
            imp += s_gates[bb2][ee];
            float thr = (s_noisy[bb2][ee] > s_thr_in[bb2]) ? s_thr_in[bb2] : s_thr_out[bb2];
            float z = (s_clean[bb2][ee] - thr) / s_nstd[bb2][ee];
            ld += 0.5f * (1.0f + erff(z * 0.7071067811865476f));
        }
        s_imp[ee] = imp; s_load[ee] = ld;
    }
    __syncthreads();
    if (tid == 0) {
        float aux = 0.f;
        {
            float m = (s_imp[0] + s_imp[1] + s_imp[2] + s_imp[3]) * 0.25f;
            float var = 0.f;
            for (int i = 0; i < 4; ++i) { float d = s_imp[i] - m; var += d * d; }
            var *= (1.0f / 3.0f);
            aux += var / (m * m + 1e-10f);
        }
        {
            float m = (s_load[0] + s_load[1] + s_load[2] + s_load[3]) * 0.25f;
            float var = 0.f;
            for (int i = 0; i < 4; ++i) { float d = s_load[i] - m; var += d * d; }
            var *= (1.0f / 3.0f);
            aux += var / (m * m + 1e-10f);
        }
        loss[0] += 0.01f * aux;
    }
}

// ---------------- FC1 (MFMA): A in LDS (full K, 1 barrier), B direct-global ----------------
// grid (4, 6, 64): x = d-tile(128), y = m-tile(64), z = b*2+slot
__global__ __launch_bounds__(256, 3) void fc1_mfma(
    const short* __restrict__ Tb16, const short* __restrict__ W1t_l,
    const float* __restrict__ b1_l, const int* __restrict__ IDX,
    const float* __restrict__ GV, short* __restrict__ Hs)
{
    int z = blockIdx.z;
    int b = z >> 1;
    int e = IDX[z];
    float g = GV[z];
    int m0 = blockIdx.y * 64, n0 = blockIdx.x * 128;
    int tid = threadIdx.x;
    int wave = tid >> 6, lane = tid & 63, quad = lane >> 4, l16 = lane & 15;
    int wn = wave * 32;
    __shared__ short Al[64][360];   // stride 360 shorts = 720B -> ~2-way banks
    {   // stage full 64 x 352 A tile once
        int r = tid >> 2, c0 = (tid & 3) * 8;
        const short* src = Tb16 + ((size_t)b * NN + m0 + r) * LP + c0;
        #pragma unroll
        for (int ks = 0; ks < 11; ++ks)
            *(uint4*)&Al[r][c0 + ks * 32] = *(const uint4*)(src + ks * 32);
    }
    __syncthreads();

    const short* Bb = W1t_l + ((size_t)e * DHID + n0 + wn + l16) * LP + quad * 8;
    float4v zero4 = {0.f, 0.f, 0.f, 0.f};
    float4v acc[4][2];
    #pragma unroll
    for (int i = 0; i < 4; ++i)
        #pragma unroll
        for (int j = 0; j < 2; ++j) acc[i][j] = zero4;

    #pragma unroll
    for (int ks = 0; ks < 11; ++ks) {   // barrier-free: B loads pipeline freely
        int off = ks * 32;
        short8 bf0 = *(const short8*)(Bb + off);
        short8 bf1 = *(const short8*)(Bb + (size_t)16 * LP + off);
        short8 af[4];
        #pragma unroll
        for (int mi = 0; mi < 4; ++mi) af[mi] = *(const short8*)&Al[mi * 16 + l16][off + quad * 8];
        #pragma unroll
        for (int mi = 0; mi < 4; ++mi) {
            acc[mi][0] = __builtin_amdgcn_mfma_f32_16x16x32_bf16(af[mi], bf0, acc[mi][0], 0, 0, 0);
            acc[mi][1] = __builtin_amdgcn_mfma_f32_16x16x32_bf16(af[mi], bf1, acc[mi][1], 0, 0, 0);
        }
    }
    const float* bb = b1_l + (size_t)e * DHID;
    float bias[2];
    #pragma unroll
    for (int ni = 0; ni < 2; ++ni) bias[ni] = bb[n0 + wn + ni * 16 + l16];
    short* Ho = Hs + (size_t)z * NN * DHID;
    #pragma unroll
    for (int mi = 0; mi < 4; ++mi) {
        #pragma unroll
        for (int r = 0; r < 4; ++r) {
            int gm = m0 + mi * 16 + quad * 4 + r;   // C/D: col=lane&15, row=quad*4+reg
            if (gm >= NN) continue;
            #pragma unroll
            for (int ni = 0; ni < 2; ++ni) {
                int gd = n0 + wn + ni * 16 + l16;
                float v = acc[mi][ni][r] + bias[ni];
                Ho[(size_t)gm * DHID + gd] = f2b(g * gelu_f(v));
            }
        }
    }
}

// ---------------- FC2 (MFMA, slot-split): T += atomically Hs[z]@W2[e] + g*b2 ----------------
// grid (3, 6, 64): x = l-tile(128), y = m-tile(64), z = b*2+slot. K = 512 per block.
__global__ __launch_bounds__(256, 3) void fc2_mfma(
    const short* __restrict__ Hs, const short* __restrict__ W2t_l,
    const float* __restrict__ b2_l, float* __restrict__ T,
    const int* __restrict__ IDX, const float* __restrict__ GV)
{
    int z = blockIdx.z;
    int b = z >> 1;
    int e = IDX[z];
    float g = GV[z];
    int m0 = blockIdx.y * 64, n0 = blockIdx.x * 128;
    int tid = threadIdx.x;
    int wave = tid >> 6, lane = tid & 63, quad = lane >> 4, l16 = lane & 15;
    int wn = wave * 32;
    __shared__ short Al[64][264];   // stride 264 shorts = 528B -> 2-way frag reads
    float4v zero4 = {0.f, 0.f, 0.f, 0.f};
    float4v acc[4][2];
    #pragma unroll
    for (int i = 0; i < 4; ++i)
        #pragma unroll
        for (int j = 0; j < 2; ++j) acc[i][j] = zero4;

    int r8 = tid >> 5, c0s = (tid & 31) * 8;
    #pragma unroll
    for (int chunk = 0; chunk < 2; ++chunk) {   // K chunks of 256
        int koff = chunk * 256;
        const short* As = Hs + ((size_t)z * NN + m0) * DHID + koff;
        #pragma unroll
        for (int i = 0; i < 8; ++i)
            *(uint4*)&Al[i * 8 + r8][c0s] = *(const uint4*)(As + (size_t)(i * 8 + r8) * DHID + c0s);
        __syncthreads();
        const short* Bb = W2t_l + ((size_t)e * LL + n0 + wn + l16) * DHID + koff + quad * 8;
        #pragma unroll
        for (int ks = 0; ks < 8; ++ks) {
            int off = ks * 32;
            short8 bf0 = *(const short8*)(Bb + off);
            short8 bf1 = *(const short8*)(Bb + (size_t)16 * DHID + off);
            short8 af[4];
            #pragma unroll
            for (int mi = 0; mi < 4; ++mi) af[mi] = *(const short8*)&Al[mi * 16 + l16][off + quad * 8];
            #pragma unroll
            for (int mi = 0; mi < 4; ++mi) {
                acc[mi][0] = __builtin_amdgcn_mfma_f32_16x16x32_bf16(af[mi], bf0, acc[mi][0], 0, 0, 0);
                acc[mi][1] = __builtin_amdgcn_mfma_f32_16x16x32_bf16(af[mi], bf1, acc[mi][1], 0, 0, 0);
            }
        }
        __syncthreads();
    }
    const float* b2e = b2_l + (size_t)e * LL;
    float bias[2]; int glc[2];
    #pragma unroll
    for (int ni = 0; ni < 2; ++ni) {
        int gl = n0 + wn + ni * 16 + l16;
        glc[ni] = gl;
        bias[ni] = (gl < LL) ? (g * b2e[gl]) : 0.f;
    }
    float* Tb = T + (size_t)b * NN * LL;
    #pragma unroll
    for (int mi = 0; mi < 4; ++mi) {
        #pragma unroll
        for (int r = 0; r < 4; ++r) {
            int gm = m0 + mi * 16 + quad * 4 + r;
            if (gm >= NN) continue;
            #pragma unroll
            for (int ni = 0; ni < 2; ++ni) {
                if (glc[ni] < LL)
                    unsafeAtomicAdd(&Tb[(size_t)gm * LL + glc[ni]], acc[mi][ni][r] + bias[ni]);
            }
        }
    }
}

// ---------------- T -> Tb16 mirror refresh + gate-sum accumulation for next layer ----------------
// grid (11, 32): x = m-tile(32), y = b
__global__ __launch_bounds__(256) void t2b16_kernel(
    const float* __restrict__ T, short* __restrict__ Tb16, float* __restrict__ G)
{
    int mt = blockIdx.x, b = blockIdx.y;
    int m0 = mt * 32;
    int tid = threadIdx.x;
    #pragma unroll
    for (int i = 0; i < 11; ++i) {
        int idx = tid + i * 256;
        if (idx < 2688) {
            int r = idx / 84, cq = (idx - r * 84) * 4;
            int gm = m0 + r;
            if (gm < NN) {
                float4 v = *(const float4*)&T[(size_t)(b * NN + gm) * LL + cq];
                union { short s[4]; uint2 u; } pk;
                pk.s[0] = f2b(v.x); pk.s[1] = f2b(v.y); pk.s[2] = f2b(v.z); pk.s[3] = f2b(v.w);
                *(uint2*)&Tb16[(size_t)(b * NN + gm) * LP + cq] = pk.u;
            }
        }
    }
    if (tid < 64) {   // zero K-pad cols 336..352
        int r = tid >> 1, gm = m0 + r;
        if (gm < NN)
            *(uint4*)&Tb16[(size_t)(b * NN + gm) * LP + 336 + (tid & 1) * 8] = make_uint4(0, 0, 0, 0);
    }
    if (tid < 84) {   // column partial sums over this block's rows -> G (zeroed by gating)
        int rmax = NN - m0; if (rmax > 32) rmax = 32;
        float4 s = make_float4(0.f, 0.f, 0.f, 0.f);
        const float* tp = T + (size_t)(b * NN + m0) * LL + tid * 4;
        for (int r = 0; r < rmax; ++r, tp += LL) {
            float4 v = *(const float4*)tp;
            s.x += v.x; s.y += v.y; s.z += v.z; s.w += v.w;
        }
        float* gp = G + b * LL + tid * 4;
        unsafeAtomicAdd(gp + 0, s.x);
        unsafeAtomicAdd(gp + 1, s.y);
        unsafeAtomicAdd(gp + 2, s.z);
        unsafeAtomicAdd(gp + 3, s.w);
    }
}

// ---------------- projection head v2: 32-row tiles, 2 barriers, direct-global weights ----------------
// grid 321 (= MROWS/32 exactly), 256 thr.
__global__ __launch_bounds__(256) void proj_fused(
    const short* __restrict__ Tb16,
    const short* __restrict__ p1wb, const float* __restrict__ p1b,
    const short* __restrict__ p2wb, const float* __restrict__ p2b,
    float* __restrict__ out)
{
    __shared__ short Al[32][360];   // 32 x 352 A-tile (stride 360 -> ~2-way banks)
    __shared__ short Hp[32][104];   // 32 x 96 tanh-hidden (stride 104 -> 2-way)
    int m0 = blockIdx.x * 32;
    int tid = threadIdx.x;
    int wave = tid >> 6, lane = tid & 63, quad = lane >> 4, l16 = lane & 15;
    float4v zero4 = {0.f, 0.f, 0.f, 0.f};

    // stage A once: 1408 uint4 (32*352*2B)
    #pragma unroll
    for (int i = 0; i < 6; ++i) {
        int idx = tid + i * 256;
        if (idx < 1408) {
            int r = idx / 44, c = (idx - r * 44) * 8;
            *(uint4*)&Al[r][c] = *(const uint4*)(Tb16 + (size_t)(m0 + r) * LP + c);
        }
    }
    __syncthreads();

    // ---- phase 1: Hp = tanh(A @ p1w^T + p1b). wave: rf = wave&1, cf = (wave>>1)+2j ----
    {
        int rf = wave & 1, cfb = wave >> 1;
        float4v acc1[3];
        #pragma unroll
        for (int j = 0; j < 3; ++j) acc1[j] = zero4;
        const short* B1p0 = p1wb + (size_t)(cfb * 16 + l16) * LP + quad * 8;
        #pragma unroll
        for (int ks = 0; ks < 11; ++ks) {   // barrier-free; B direct-global (L1/L2-served)
            int off = ks * 32;
            short8 af = *(const short8*)&Al[rf * 16 + l16][off + quad * 8];
            #pragma unroll
            for (int j = 0; j < 3; ++j) {
                short8 bf = *(const short8*)(B1p0 + (size_t)j * 32 * LP + off);
                acc1[j] = __builtin_amdgcn_mfma_f32_16x16x32_bf16(af, bf, acc1[j], 0, 0, 0);
            }
        }
        #pragma unroll
        for (int j = 0; j < 3; ++j) {
            int p = (cfb + 2 * j) * 16 + l16;
            float pb = p1b[p];
            #pragma unroll
            for (int r = 0; r < 4; ++r)
                Hp[rf * 16 + quad * 4 + r][p] = f2b(fast_tanh(acc1[j][r] + pb));
        }
    }
    __syncthreads();

    // ---- phase 2 (transposed): c-rows = wave*3+mi frags, node cols; B direct-global ----
    float4v acc2[3][2];
    #pragma unroll
    for (int i = 0; i < 3; ++i)
        #pragma unroll
        for (int j = 0; j < 2; ++j) acc2[i][j] = zero4;
    #pragma unroll
    for (int kc = 0; kc < 3; ++kc) {
        int off = kc * 32 + quad * 8;
        short8 bfv0 = *(const short8*)&Hp[l16][off];
        short8 bfv1 = *(const short8*)&Hp[16 + l16][off];
        #pragma unroll
        for (int mi = 0; mi < 3; ++mi) {
            int cf = wave * 3 + mi;
            short8 af = *(const short8*)(p2wb + (size_t)(cf * 16 + l16) * PP + off);
            acc2[mi][0] = __builtin_amdgcn_mfma_f32_16x16x32_bf16(af, bfv0, acc2[mi][0], 0, 0, 0);
            acc2[mi][1] = __builtin_amdgcn_mfma_f32_16x16x32_bf16(af, bfv1, acc2[mi][1], 0, 0, 0);
        }
    }
    // stores: lane l16 -> consecutive node (64B runs per quad); 321*32 = MROWS exactly
    int bqv[2], ndv[2];
    #pragma unroll
    for (int ni = 0; ni < 2; ++ni) {
        int gm = m0 + ni * 16 + l16;
        int bq = gm / NN;
        bqv[ni] = bq; ndv[ni] = gm - bq * NN;
    }
    #pragma unroll
    for (int mi = 0; mi < 3; ++mi) {
        #pragma unroll
        for (int r = 0; r < 4; ++r) {
            int c = (wave * 3 + mi) * 16 + quad * 4 + r;
            float pb = p2b[c];
            int p = c >> 1;
            if ((r & 1) == 0) {               // c even -> mean
                #pragma unroll
                for (int ni = 0; ni < 2; ++ni) {
                    float v = acc2[mi][ni][r] + pb;
                    out[((size_t)bqv[ni] * PP + p) * NN + ndv[ni]] = v;
                }
            } else {                          // c odd -> std
                #pragma unroll
                for (int ni = 0; ni < 2; ++ni) {
                    float v = acc2[mi][ni][r] + pb;
                    out[BPN + 1 + ((size_t)bqv[ni] * PP + p) * NN + ndv[ni]] = softplus_f(v) + 1e-6f;
                }
            }
        }
    }
}

__global__ void loss_write_kernel(const float* __restrict__ loss, float* __restrict__ out)
{
    if (threadIdx.x == 0) out[BPN] = loss[0];
}

extern "C" void kernel_launch(void* const* d_in, const int* in_sizes, int n_in,
                              void* d_out, int out_size, void* d_ws, size_t ws_size,
                              hipStream_t stream)
{
    const float* x     = (const float*)d_in[0];
    const float* noise = (const float*)d_in[1];
    const float* wg    = (const float*)d_in[2];
    const float* wn    = (const float*)d_in[3];
    const float* W1    = (const float*)d_in[4];
    const float* b1    = (const float*)d_in[5];
    const float* W2    = (const float*)d_in[6];
    const float* b2    = (const float*)d_in[7];
    const float* p1w   = (const float*)d_in[8];
    const float* p1b   = (const float*)d_in[9];
    const float* p2w   = (const float*)d_in[10];
    const float* p2b   = (const float*)d_in[11];
    float* out = (float*)d_out;

    float* ws   = (float*)d_ws;
    float* T    = ws;                          // STOT fp32 (stride LL)
    float* G8   = T + STOT;                    // 8*BB*LL
    float* G    = G8 + 8 * BB * LL;            // BB*LL
    float* LOSS = G + BB * LL;                 // 8
    float* GV   = LOSS + 8;                    // 64
    int*   IDX  = (int*)(GV + 64);             // 64
    float* MU   = (float*)(IDX + 64);          // BB*NN
    float* IV   = MU + MROWS;                  // BB*NN
    short* W1t  = (short*)(IV + MROWS);        // NLAYERS*EE*DHID*LP bf16 [le][d][k]
    short* W2t  = W1t + (size_t)NLAYERS * EE * DHID * LP;  // NLAYERS*EE*LL*DHID
    short* p1wb = W2t + (size_t)NLAYERS * EE * LL * DHID;  // 96*LP (K-padded)
    short* p2wb = p1wb + PP * LP;              // 192*96
    short* Tb16 = p2wb + 2 * PP * PP;          // MROWS x LP bf16 mirror of T
    short* Hs   = Tb16 + (size_t)(MROWS + 64) * LP;  // 64*NN rows + slack x DHID bf16

    revin_stats<<<dim3(BB, 6), 256, 0, stream>>>(x, MU, IV, LOSS);
    revin_tn<<<dim3(BB, 6, 7), 256, 0, stream>>>(x, MU, IV, T, Tb16);

    pcvt_kernel<<<(PP * LP + 2 * PP * PP + 255) / 256, 256, 0, stream>>>(p1w, p2w, p1wb, p2wb);
    wtrans_kernel<<<dim3(8, 6, NLAYERS * EE), 256, 0, stream>>>(W1, W1t, LL, DHID, LP);
    wtrans_kernel<<<dim3(6, 8, NLAYERS * EE), 256, 0, stream>>>(W2, W2t, DHID, LL, DHID);

    // layer-0 gate sums
    gmean_part<<<dim3(BB, 8), 384, 0, stream>>>(T, G8);
    gmean_red<<<BB, 384, 0, stream>>>(G8, G);

    for (int l = 0; l < NLAYERS; ++l) {
        gating_kernel<<<1, 512, 0, stream>>>(G, wg + (size_t)l * LL * EE, wn + (size_t)l * LL * EE,
                                             noise + (size_t)l * BB * EE, IDX, GV, LOSS);
        fc1_mfma<<<dim3(4, 6, 64), 256, 0, stream>>>(
            Tb16, W1t + (size_t)l * EE * DHID * LP, b1 + (size_t)l * EE * DHID, IDX, GV, Hs);
        fc2_mfma<<<dim3(3, 6, 64), 256, 0, stream>>>(
            Hs, W2t + (size_t)l * EE * LL * DHID, b2 + (size_t)l * EE * LL, T, IDX, GV);
        t2b16_kernel<<<dim3(11, BB), 256, 0, stream>>>(T, Tb16, G);
    }
    proj_fused<<<321, 256, 0, stream>>>(Tb16, p1wb, p1b, p2wb, p2b, out);
    loss_write_kernel<<<1, 64, 0, stream>>>(LOSS, out);
}

// Round 12
// 425.075 us; speedup vs baseline: 1.3719x; 1.0443x over previous
//
#include <hip/hip_runtime.h>
#include <hip/hip_bf16.h>

#define NLAYERS 3
#define BB 32
#define LL 336
#define LP 352                 // K-padded stride for Tb16 / W1t / p1wb (zeros in pad)
#define NN 321
#define EE 4
#define DHID 512
#define PP 96
#define STOT (BB*NN*LL)        // 3451392
#define MROWS (BB*NN)          // 10272
#define BPN ((size_t)BB*PP*NN) // 986112

typedef __attribute__((ext_vector_type(8))) short short8;
typedef __attribute__((ext_vector_type(4))) float float4v;

union BF { __hip_bfloat16 h; short s; };

__device__ __forceinline__ short f2b(float f) { BF u; u.h = __float2bfloat16(f); return u.s; }

__device__ __forceinline__ float fast_tanh(float y) {
    float e = __expf(2.0f * y);
    return 1.0f - 2.0f / (e + 1.0f);   // exact limits at +-inf
}
__device__ __forceinline__ float gelu_f(float x) {
    return 0.5f * x * (1.0f + fast_tanh(0.7978845608028654f * (x + 0.044715f * x * x * x)));
}
__device__ __forceinline__ float softplus_f(float x) {
    return fmaxf(x, 0.0f) + log1pf(expf(-fabsf(x)));
}

// ---------------- RevIN stats: mu/inv per (b,n); also zeros loss ----------------
__global__ __launch_bounds__(256) void revin_stats(
    const float* __restrict__ x, float* __restrict__ MU, float* __restrict__ IV,
    float* __restrict__ loss)
{
    int b = blockIdx.x, nt = blockIdx.y;
    int tid = threadIdx.x;
    if (b == 0 && nt == 0 && tid == 0) loss[0] = 0.0f;
    int ni = tid & 63, lc = tid >> 6;
    int n = nt * 64 + ni;
    float s = 0.f, ss = 0.f;
    if (n < NN) {
        const float* xp = x + ((size_t)b * LL + lc * 84) * NN + n;
        for (int l = 0; l < 84; ++l, xp += NN) {
            float v = *xp; s += v; ss = fmaf(v, v, ss);
        }
    }
    __shared__ float Ss[4][64], Sq[4][64];
    Ss[lc][ni] = s; Sq[lc][ni] = ss;
    __syncthreads();
    if (lc == 0 && n < NN) {
        float st = ((Ss[0][ni] + Ss[1][ni]) + Ss[2][ni]) + Ss[3][ni];
        float sq = ((Sq[0][ni] + Sq[1][ni]) + Sq[2][ni]) + Sq[3][ni];
        float mu  = st * (1.0f / LL);
        float var = sq * (1.0f / LL) - mu * mu;   // ddof=0
        float inv = 1.0f / sqrtf(var + 1e-5f);
        MU[b * NN + n] = mu;
        IV[b * NN + n] = inv;
    }
}

// ---------------- RevIN transpose+normalize: T (stride LL) + Tb16 (stride LP) ----------------
__global__ __launch_bounds__(256) void revin_tn(
    const float* __restrict__ x, const float* __restrict__ MU, const float* __restrict__ IV,
    float* __restrict__ T, short* __restrict__ Tb16)
{
    int b = blockIdx.x, nt = blockIdx.y, lt = blockIdx.z;
    int n0 = nt * 64, l0 = lt * 48;
    __shared__ float Ls[48][65];
    int tid = threadIdx.x;
    #pragma unroll
    for (int i = 0; i < 12; ++i) {
        int lin = tid + i * 256;
        int li = lin >> 6, ni = lin & 63;
        int n = n0 + ni;
        Ls[li][ni] = (n < NN) ? x[((size_t)b * LL + l0 + li) * NN + n] : 0.f;
    }
    __syncthreads();
    int r = tid >> 2, q = tid & 3;
    int n = n0 + r;
    if (n >= NN) return;
    float mu = MU[b * NN + n], iv = IV[b * NN + n];
    size_t rowf = (size_t)(b * NN + n) * LL + l0;
    size_t rowb = (size_t)(b * NN + n) * LP + l0;
    #pragma unroll
    for (int k = 0; k < 3; ++k) {
        int c = (q + 4 * k) * 4;
        float4 v;
        v.x = (Ls[c    ][r] - mu) * iv;
        v.y = (Ls[c + 1][r] - mu) * iv;
        v.z = (Ls[c + 2][r] - mu) * iv;
        v.w = (Ls[c + 3][r] - mu) * iv;
        *(float4*)&T[rowf + c] = v;
        union { short s[4]; uint2 u; } pk;
        pk.s[0] = f2b(v.x); pk.s[1] = f2b(v.y); pk.s[2] = f2b(v.z); pk.s[3] = f2b(v.w);
        *(uint2*)&Tb16[rowb + c] = pk.u;
    }
    if (lt == 6 && q == 3) {   // zero the K-pad cols 336..352
        size_t base = (size_t)(b * NN + n) * LP;
        *(uint4*)&Tb16[base + 336] = make_uint4(0, 0, 0, 0);
        *(uint4*)&Tb16[base + 344] = make_uint4(0, 0, 0, 0);
    }
}

// ---------------- tiled transpose+convert: dst[d][k(KS-strided)] <- bf16(src[k][d]) ----------------
__global__ __launch_bounds__(256) void wtrans_kernel(
    const float* __restrict__ src0, short* __restrict__ dst0, int K, int D, int KS)
{
    int le = blockIdx.z;
    const float* src = src0 + (size_t)le * K * D;
    short* dst = dst0 + (size_t)le * D * KS;
    int d0 = blockIdx.x * 64, k0 = blockIdx.y * 64;
    __shared__ short Ws[64][72];
    int tid = threadIdx.x;
    #pragma unroll
    for (int i = 0; i < 16; ++i) {
        int lin = tid + i * 256;
        int ki = lin >> 6, dj = lin & 63;
        int k = k0 + ki, d = d0 + dj;
        Ws[ki][dj] = (k < K && d < D) ? f2b(src[(size_t)k * D + d]) : (short)0;
    }
    __syncthreads();
    int di = tid >> 2, d = d0 + di;
    if (d >= D) return;
    #pragma unroll
    for (int kp = 0; kp < 2; ++kp) {
        int kj = ((tid & 3) + 4 * kp) * 8;
        if (k0 + kj >= KS) continue;
        union { short s[8]; uint4 u; } pk;
        #pragma unroll
        for (int j = 0; j < 8; ++j) pk.s[j] = Ws[kj + j][di];
        *(uint4*)(dst + (size_t)d * KS + k0 + kj) = pk.u;
    }
}

// ---------------- small convert for p1w (pad to LP) / p2w ----------------
__global__ __launch_bounds__(256) void pcvt_kernel(
    const float* __restrict__ p1w, const float* __restrict__ p2w,
    short* __restrict__ p1wb, short* __restrict__ p2wb)
{
    int i = blockIdx.x * 256 + threadIdx.x;
    if (i < PP * LP) {
        int n = i / LP, k = i - n * LP;
        p1wb[i] = (k < LL) ? f2b(p1w[n * LL + k]) : (short)0;
    } else if (i < PP * LP + 2 * PP * PP) {
        int j = i - PP * LP;
        p2wb[j] = f2b(p2w[j]);
    }
}

// ---------------- gate features (layer 0 only): 8-way partial sums over n ----------------
__global__ __launch_bounds__(384) void gmean_part(
    const float* __restrict__ T, float* __restrict__ G8)
{
    int b = blockIdx.x, c = blockIdx.y;
    int l = threadIdx.x;
    if (l >= LL) return;
    int n_lo = c * 41, n_hi = (NN < n_lo + 41) ? NN : (n_lo + 41);
    const float* tp = T + ((size_t)b * NN + n_lo) * LL + l;
    float s = 0.f;
    for (int n = n_lo; n < n_hi; ++n, tp += LL) s += *tp;
    G8[((size_t)c * BB + b) * LL + l] = s;
}

__global__ __launch_bounds__(384) void gmean_red(
    const float* __restrict__ G8, float* __restrict__ G)
{
    int b = blockIdx.x;
    int l = threadIdx.x;
    if (l >= LL) return;
    float s = 0.f;
    #pragma unroll
    for (int c = 0; c < 8; ++c) s += G8[((size_t)c * BB + b) * LL + l];
    G[b * LL + l] = s;     // SUM (gating applies 1/NN)
}

// ---------------- noisy top-k gating + aux loss; G holds SUMS; zeroes G at end ----------------
__global__ __launch_bounds__(512) void gating_kernel(
    float* __restrict__ G, const float* __restrict__ wg,
    const float* __restrict__ wn, const float* __restrict__ noise,
    int* __restrict__ IDX, float* __restrict__ GV, float* __restrict__ loss)
{
    __shared__ float pc[BB][EE][4], pn[BB][EE][4];
    __shared__ float s_clean[BB][EE], s_nstd[BB][EE], s_noisy[BB][EE], s_gates[BB][EE];
    __shared__ float s_thr_in[BB], s_thr_out[BB];
    __shared__ float s_imp[EE], s_load[EE];
    int tid = threadIdx.x;
    {
        int b = tid >> 4, e = (tid >> 2) & 3, sub = tid & 3;
        float c = 0.f, nr = 0.f;
        const float* gp = G + b * LL;
        for (int l = sub * 84; l < sub * 84 + 84; ++l) {
            float gv = gp[l] * (1.0f / NN);
            c  = fmaf(gv, wg[l * EE + e], c);
            nr = fmaf(gv, wn[l * EE + e], nr);
        }
        pc[b][e][sub] = c; pn[b][e][sub] = nr;
    }
    __syncthreads();
    // all G reads done; zero G for next layer's accumulation
    for (int i2 = tid; i2 < BB * LL; i2 += 512) G[i2] = 0.0f;
    int b = tid >> 2, e = tid & 3;   // valid for tid < 128
    if (tid < 128) {
        float c  = ((pc[b][e][0] + pc[b][e][1]) + pc[b][e][2]) + pc[b][e][3];
        float nr = ((pn[b][e][0] + pn[b][e][1]) + pn[b][e][2]) + pn[b][e][3];
        float nstd  = softplus_f(nr) + 1e-2f;
        float noisy = fmaf(noise[b * EE + e], nstd, c);
        s_clean[b][e] = c; s_nstd[b][e] = nstd; s_noisy[b][e] = noisy;
    }
    __syncthreads();
    if (tid < 128 && e == 0) {
        float v[4];
        #pragma unroll
        for (int i = 0; i < 4; ++i) v[i] = s_noisy[b][i];
        int i0 = 0;
        for (int i = 1; i < 4; ++i) if (v[i] > v[i0]) i0 = i;
        int i1 = -1;
        for (int i = 0; i < 4; ++i) { if (i == i0) continue; if (i1 < 0 || v[i] > v[i1]) i1 = i; }
        float m3 = -1e30f;
        for (int i = 0; i < 4; ++i) { if (i == i0 || i == i1) continue; if (v[i] > m3) m3 = v[i]; }
        float e1  = expf(v[i1] - v[i0]);
        float invd = 1.0f / (1.0f + e1);
        #pragma unroll
        for (int i = 0; i < 4; ++i) s_gates[b][i] = 0.f;
        s_gates[b][i0] = invd;
        s_gates[b][i1] = e1 * invd;
        s_thr_in[b]  = m3;       // (k+1)-th value
        s_thr_out[b] = v[i1];    // k-th value
        IDX[2*b] = i0; IDX[2*b+1] = i1;
        GV[2*b] = invd; GV[2*b+1] = e1 * invd;
    }
    __syncthreads();
    if (tid < EE) {
        int ee = tid;
        float imp = 0.f, ld = 0.f;
        for (int bb2 = 0; bb2 < BB; ++bb2) {
            imp += s_gates[bb2][ee];
            float thr = (s_noisy[bb2][ee] > s_thr_in[bb2]) ? s_thr_in[bb2] : s_thr_out[bb2];
            float z = (s_clean[bb2][ee] - thr) / s_nstd[bb2][ee];
            ld += 0.5f * (1.0f + erff(z * 0.7071067811865476f));
        }
        s_imp[ee] = imp; s_load[ee] = ld;
    }
    __syncthreads();
    if (tid == 0) {
        float aux = 0.f;
        {
            float m = (s_imp[0] + s_imp[1] + s_imp[2] + s_imp[3]) * 0.25f;
            float var = 0.f;
            for (int i = 0; i < 4; ++i) { float d = s_imp[i] - m; var += d * d; }
            var *= (1.0f / 3.0f);
            aux += var / (m * m + 1e-10f);
        }
        {
            float m = (s_load[0] + s_load[1] + s_load[2] + s_load[3]) * 0.25f;
            float var = 0.f;
            for (int i = 0; i < 4; ++i) { float d = s_load[i] - m; var += d * d; }
            var *= (1.0f / 3.0f);
            aux += var / (m * m + 1e-10f);
        }
        loss[0] += 0.01f * aux;
    }
}

// ---------------- FC1 (MFMA): A in LDS, B direct-global; XCD-swizzled flat grid ----------------
// flat grid 1536 = 4 d-tiles x 6 m-tiles x 64 (b,slot). The 8 blocks sharing an A-tile
// (4 d-tiles x 2 slots of same b) get indices differing by 8 -> same XCD (i%8 round-robin).
__global__ __launch_bounds__(256, 3) void fc1_mfma(
    const short* __restrict__ Tb16, const short* __restrict__ W1t_l,
    const float* __restrict__ b1_l, const int* __restrict__ IDX,
    const float* __restrict__ GV, short* __restrict__ Hs)
{
    int i = blockIdx.x;
    int low = i & 7, rest = i >> 3;
    int v = rest & 7, ghi = rest >> 3;       // v in [0,8), ghi in [0,24)
    int g = ghi * 8 + low;                   // [0,192)
    int y = g % 6, b = g / 6;
    int xt = v & 3, slot = v >> 2;
    int z = b * 2 + slot;
    int e = IDX[z];
    float gt = GV[z];
    int m0 = y * 64, n0 = xt * 128;
    int tid = threadIdx.x;
    int wave = tid >> 6, lane = tid & 63, quad = lane >> 4, l16 = lane & 15;
    int wn = wave * 32;
    __shared__ short Al[64][360];   // stride 360 shorts = 720B -> ~2-way banks
    {   // stage full 64 x 352 A tile once
        int r = tid >> 2, c0 = (tid & 3) * 8;
        const short* src = Tb16 + ((size_t)b * NN + m0 + r) * LP + c0;
        #pragma unroll
        for (int ks = 0; ks < 11; ++ks)
            *(uint4*)&Al[r][c0 + ks * 32] = *(const uint4*)(src + ks * 32);
    }
    __syncthreads();

    const short* Bb = W1t_l + ((size_t)e * DHID + n0 + wn + l16) * LP + quad * 8;
    float4v zero4 = {0.f, 0.f, 0.f, 0.f};
    float4v acc[4][2];
    #pragma unroll
    for (int a = 0; a < 4; ++a)
        #pragma unroll
        for (int j = 0; j < 2; ++j) acc[a][j] = zero4;

    #pragma unroll
    for (int ks = 0; ks < 11; ++ks) {   // barrier-free: B loads pipeline freely
        int off = ks * 32;
        short8 bf0 = *(const short8*)(Bb + off);
        short8 bf1 = *(const short8*)(Bb + (size_t)16 * LP + off);
        short8 af[4];
        #pragma unroll
        for (int mi = 0; mi < 4; ++mi) af[mi] = *(const short8*)&Al[mi * 16 + l16][off + quad * 8];
        #pragma unroll
        for (int mi = 0; mi < 4; ++mi) {
            acc[mi][0] = __builtin_amdgcn_mfma_f32_16x16x32_bf16(af[mi], bf0, acc[mi][0], 0, 0, 0);
            acc[mi][1] = __builtin_amdgcn_mfma_f32_16x16x32_bf16(af[mi], bf1, acc[mi][1], 0, 0, 0);
        }
    }
    const float* bb = b1_l + (size_t)e * DHID;
    float bias[2];
    #pragma unroll
    for (int ni = 0; ni < 2; ++ni) bias[ni] = bb[n0 + wn + ni * 16 + l16];
    short* Ho = Hs + (size_t)z * NN * DHID;
    #pragma unroll
    for (int mi = 0; mi < 4; ++mi) {
        #pragma unroll
        for (int r = 0; r < 4; ++r) {
            int gm = m0 + mi * 16 + quad * 4 + r;   // C/D: col=lane&15, row=quad*4+reg
            if (gm >= NN) continue;
            #pragma unroll
            for (int ni = 0; ni < 2; ++ni) {
                int gd = n0 + wn + ni * 16 + l16;
                float vv = acc[mi][ni][r] + bias[ni];
                Ho[(size_t)gm * DHID + gd] = f2b(gt * gelu_f(vv));
            }
        }
    }
}

// ---------------- FC2 (MFMA, slot-split, XCD-swizzled): T += atomic Hs[z]@W2[e] + g*b2 ----
// flat grid 1152 = 3 l-tiles x 6 m-tiles x 64 (b,slot). The 3 blocks sharing an A-tile
// (3 l-tiles of same (m,z)) get indices differing by 8 -> same XCD.
__global__ __launch_bounds__(256, 4) void fc2_mfma(
    const short* __restrict__ Hs, const short* __restrict__ W2t_l,
    const float* __restrict__ b2_l, float* __restrict__ T,
    const int* __restrict__ IDX, const float* __restrict__ GV)
{
    int i = blockIdx.x;
    int low = i & 7, rest = i >> 3;
    int v = rest % 3, ghi = rest / 3;        // v in [0,3), ghi in [0,48)
    int g = ghi * 8 + low;                   // [0,384)
    int y = g % 6, z = g / 6;
    int b = z >> 1;
    int e = IDX[z];
    float gt = GV[z];
    int m0 = y * 64, n0 = v * 128;
    int tid = threadIdx.x;
    int wave = tid >> 6, lane = tid & 63, quad = lane >> 4, l16 = lane & 15;
    int wn = wave * 32;
    __shared__ short Al[64][264];   // stride 264 shorts = 528B -> 2-way frag reads
    float4v zero4 = {0.f, 0.f, 0.f, 0.f};
    float4v acc[4][2];
    #pragma unroll
    for (int a = 0; a < 4; ++a)
        #pragma unroll
        for (int j = 0; j < 2; ++j) acc[a][j] = zero4;

    int r8 = tid >> 5, c0s = (tid & 31) * 8;
    #pragma unroll
    for (int chunk = 0; chunk < 2; ++chunk) {   // K chunks of 256
        int koff = chunk * 256;
        const short* As = Hs + ((size_t)z * NN + m0) * DHID + koff;
        #pragma unroll
        for (int a = 0; a < 8; ++a)
            *(uint4*)&Al[a * 8 + r8][c0s] = *(const uint4*)(As + (size_t)(a * 8 + r8) * DHID + c0s);
        __syncthreads();
        const short* Bb = W2t_l + ((size_t)e * LL + n0 + wn + l16) * DHID + koff + quad * 8;
        #pragma unroll
        for (int ks = 0; ks < 8; ++ks) {
            int off = ks * 32;
            short8 bf0 = *(const short8*)(Bb + off);
            short8 bf1 = *(const short8*)(Bb + (size_t)16 * DHID + off);
            short8 af[4];
            #pragma unroll
            for (int mi = 0; mi < 4; ++mi) af[mi] = *(const short8*)&Al[mi * 16 + l16][off + quad * 8];
            #pragma unroll
            for (int mi = 0; mi < 4; ++mi) {
                acc[mi][0] = __builtin_amdgcn_mfma_f32_16x16x32_bf16(af[mi], bf0, acc[mi][0], 0, 0, 0);
                acc[mi][1] = __builtin_amdgcn_mfma_f32_16x16x32_bf16(af[mi], bf1, acc[mi][1], 0, 0, 0);
            }
        }
        __syncthreads();
    }
    const float* b2e = b2_l + (size_t)e * LL;
    float bias[2]; int glc[2];
    #pragma unroll
    for (int ni = 0; ni < 2; ++ni) {
        int gl = n0 + wn + ni * 16 + l16;
        glc[ni] = gl;
        bias[ni] = (gl < LL) ? (gt * b2e[gl]) : 0.f;
    }
    float* Tb = T + (size_t)b * NN * LL;
    #pragma unroll
    for (int mi = 0; mi < 4; ++mi) {
        #pragma unroll
        for (int r = 0; r < 4; ++r) {
            int gm = m0 + mi * 16 + quad * 4 + r;
            if (gm >= NN) continue;
            #pragma unroll
            for (int ni = 0; ni < 2; ++ni) {
                if (glc[ni] < LL)
                    unsafeAtomicAdd(&Tb[(size_t)gm * LL + glc[ni]], acc[mi][ni][r] + bias[ni]);
            }
        }
    }
}

// ---------------- T -> Tb16 mirror refresh + gate-sum accumulation for next layer ----------------
// grid (11, 32): x = m-tile(32), y = b
__global__ __launch_bounds__(256) void t2b16_kernel(
    const float* __restrict__ T, short* __restrict__ Tb16, float* __restrict__ G)
{
    int mt = blockIdx.x, b = blockIdx.y;
    int m0 = mt * 32;
    int tid = threadIdx.x;
    #pragma unroll
    for (int i = 0; i < 11; ++i) {
        int idx = tid + i * 256;
        if (idx < 2688) {
            int r = idx / 84, cq = (idx - r * 84) * 4;
            int gm = m0 + r;
            if (gm < NN) {
                float4 v = *(const float4*)&T[(size_t)(b * NN + gm) * LL + cq];
                union { short s[4]; uint2 u; } pk;
                pk.s[0] = f2b(v.x); pk.s[1] = f2b(v.y); pk.s[2] = f2b(v.z); pk.s[3] = f2b(v.w);
                *(uint2*)&Tb16[(size_t)(b * NN + gm) * LP + cq] = pk.u;
            }
        }
    }
    if (tid < 64) {   // zero K-pad cols 336..352
        int r = tid >> 1, gm = m0 + r;
        if (gm < NN)
            *(uint4*)&Tb16[(size_t)(b * NN + gm) * LP + 336 + (tid & 1) * 8] = make_uint4(0, 0, 0, 0);
    }
    if (tid < 84) {   // column partial sums over this block's rows -> G (zeroed by gating)
        int rmax = NN - m0; if (rmax > 32) rmax = 32;
        float4 s = make_float4(0.f, 0.f, 0.f, 0.f);
        const float* tp = T + (size_t)(b * NN + m0) * LL + tid * 4;
        for (int r = 0; r < rmax; ++r, tp += LL) {
            float4 v = *(const float4*)tp;
            s.x += v.x; s.y += v.y; s.z += v.z; s.w += v.w;
        }
        float* gp = G + b * LL + tid * 4;
        unsafeAtomicAdd(gp + 0, s.x);
        unsafeAtomicAdd(gp + 1, s.y);
        unsafeAtomicAdd(gp + 2, s.z);
        unsafeAtomicAdd(gp + 3, s.w);
    }
}

// ---------------- projection head v2: 32-row tiles, 2 barriers, direct-global weights ----------------
// grid 321 (= MROWS/32 exactly), 256 thr.
__global__ __launch_bounds__(256) void proj_fused(
    const short* __restrict__ Tb16,
    const short* __restrict__ p1wb, const float* __restrict__ p1b,
    const short* __restrict__ p2wb, const float* __restrict__ p2b,
    float* __restrict__ out)
{
    __shared__ short Al[32][360];   // 32 x 352 A-tile (stride 360 -> ~2-way banks)
    __shared__ short Hp[32][104];   // 32 x 96 tanh-hidden (stride 104 -> 2-way)
    int m0 = blockIdx.x * 32;
    int tid = threadIdx.x;
    int wave = tid >> 6, lane = tid & 63, quad = lane >> 4, l16 = lane & 15;
    float4v zero4 = {0.f, 0.f, 0.f, 0.f};

    // stage A once: 1408 uint4 (32*352*2B)
    #pragma unroll
    for (int i = 0; i < 6; ++i) {
        int idx = tid + i * 256;
        if (idx < 1408) {
            int r = idx / 44, c = (idx - r * 44) * 8;
            *(uint4*)&Al[r][c] = *(const uint4*)(Tb16 + (size_t)(m0 + r) * LP + c);
        }
    }
    __syncthreads();

    // ---- phase 1: Hp = tanh(A @ p1w^T + p1b). wave: rf = wave&1, cf = (wave>>1)+2j ----
    {
        int rf = wave & 1, cfb = wave >> 1;
        float4v acc1[3];
        #pragma unroll
        for (int j = 0; j < 3; ++j) acc1[j] = zero4;
        const short* B1p0 = p1wb + (size_t)(cfb * 16 + l16) * LP + quad * 8;
        #pragma unroll
        for (int ks = 0; ks < 11; ++ks) {   // barrier-free; B direct-global (L1/L2-served)
            int off = ks * 32;
            short8 af = *(const short8*)&Al[rf * 16 + l16][off + quad * 8];
            #pragma unroll
            for (int j = 0; j < 3; ++j) {
                short8 bf = *(const short8*)(B1p0 + (size_t)j * 32 * LP + off);
                acc1[j] = __builtin_amdgcn_mfma_f32_16x16x32_bf16(af, bf, acc1[j], 0, 0, 0);
            }
        }
        #pragma unroll
        for (int j = 0; j < 3; ++j) {
            int p = (cfb + 2 * j) * 16 + l16;
            float pb = p1b[p];
            #pragma unroll
            for (int r = 0; r < 4; ++r)
                Hp[rf * 16 + quad * 4 + r][p] = f2b(fast_tanh(acc1[j][r] + pb));
        }
    }
    __syncthreads();

    // ---- phase 2 (transposed): c-rows = wave*3+mi frags, node cols; B direct-global ----
    float4v acc2[3][2];
    #pragma unroll
    for (int a = 0; a < 3; ++a)
        #pragma unroll
        for (int j = 0; j < 2; ++j) acc2[a][j] = zero4;
    #pragma unroll
    for (int kc = 0; kc < 3; ++kc) {
        int off = kc * 32 + quad * 8;
        short8 bfv0 = *(const short8*)&Hp[l16][off];
        short8 bfv1 = *(const short8*)&Hp[16 + l16][off];
        #pragma unroll
        for (int mi = 0; mi < 3; ++mi) {
            int cf = wave * 3 + mi;
            short8 af = *(const short8*)(p2wb + (size_t)(cf * 16 + l16) * PP + off);
            acc2[mi][0] = __builtin_amdgcn_mfma_f32_16x16x32_bf16(af, bfv0, acc2[mi][0], 0, 0, 0);
            acc2[mi][1] = __builtin_amdgcn_mfma_f32_16x16x32_bf16(af, bfv1, acc2[mi][1], 0, 0, 0);
        }
    }
    // stores: lane l16 -> consecutive node (64B runs per quad); 321*32 = MROWS exactly
    int bqv[2], ndv[2];
    #pragma unroll
    for (int ni = 0; ni < 2; ++ni) {
        int gm = m0 + ni * 16 + l16;
        int bq = gm / NN;
        bqv[ni] = bq; ndv[ni] = gm - bq * NN;
    }
    #pragma unroll
    for (int mi = 0; mi < 3; ++mi) {
        #pragma unroll
        for (int r = 0; r < 4; ++r) {
            int c = (wave * 3 + mi) * 16 + quad * 4 + r;
            float pb = p2b[c];
            int p = c >> 1;
            if ((r & 1) == 0) {               // c even -> mean
                #pragma unroll
                for (int ni = 0; ni < 2; ++ni) {
                    float v = acc2[mi][ni][r] + pb;
                    out[((size_t)bqv[ni] * PP + p) * NN + ndv[ni]] = v;
                }
            } else {                          // c odd -> std
                #pragma unroll
                for (int ni = 0; ni < 2; ++ni) {
                    float v = acc2[mi][ni][r] + pb;
                    out[BPN + 1 + ((size_t)bqv[ni] * PP + p) * NN + ndv[ni]] = softplus_f(v) + 1e-6f;
                }
            }
        }
    }
}

__global__ void loss_write_kernel(const float* __restrict__ loss, float* __restrict__ out)
{
    if (threadIdx.x == 0) out[BPN] = loss[0];
}

extern "C" void kernel_launch(void* const* d_in, const int* in_sizes, int n_in,
                              void* d_out, int out_size, void* d_ws, size_t ws_size,
                              hipStream_t stream)
{
    const float* x     = (const float*)d_in[0];
    const float* noise = (const float*)d_in[1];
    const float* wg    = (const float*)d_in[2];
    const float* wn    = (const float*)d_in[3];
    const float* W1    = (const float*)d_in[4];
    const float* b1    = (const float*)d_in[5];
    const float* W2    = (const float*)d_in[6];
    const float* b2    = (const float*)d_in[7];
    const float* p1w   = (const float*)d_in[8];
    const float* p1b   = (const float*)d_in[9];
    const float* p2w   = (const float*)d_in[10];
    const float* p2b   = (const float*)d_in[11];
    float* out = (float*)d_out;

    float* ws   = (float*)d_ws;
    float* T    = ws;                          // STOT fp32 (stride LL)
    float* G8   = T + STOT;                    // 8*BB*LL
    float* G    = G8 + 8 * BB * LL;            // BB*LL
    float* LOSS = G + BB * LL;                 // 8
    float* GV   = LOSS + 8;                    // 64
    int*   IDX  = (int*)(GV + 64);             // 64
    float* MU   = (float*)(IDX + 64);          // BB*NN
    float* IV   = MU + MROWS;                  // BB*NN
    short* W1t  = (short*)(IV + MROWS);        // NLAYERS*EE*DHID*LP bf16 [le][d][k]
    short* W2t  = W1t + (size_t)NLAYERS * EE * DHID * LP;  // NLAYERS*EE*LL*DHID
    short* p1wb = W2t + (size_t)NLAYERS * EE * LL * DHID;  // 96*LP (K-padded)
    short* p2wb = p1wb + PP * LP;              // 192*96
    short* Tb16 = p2wb + 2 * PP * PP;          // MROWS x LP bf16 mirror of T
    short* Hs   = Tb16 + (size_t)(MROWS + 64) * LP;  // 64*NN rows + slack x DHID bf16

    revin_stats<<<dim3(BB, 6), 256, 0, stream>>>(x, MU, IV, LOSS);
    revin_tn<<<dim3(BB, 6, 7), 256, 0, stream>>>(x, MU, IV, T, Tb16);

    pcvt_kernel<<<(PP * LP + 2 * PP * PP + 255) / 256, 256, 0, stream>>>(p1w, p2w, p1wb, p2wb);
    wtrans_kernel<<<dim3(8, 6, NLAYERS * EE), 256, 0, stream>>>(W1, W1t, LL, DHID, LP);
    wtrans_kernel<<<dim3(6, 8, NLAYERS * EE), 256, 0, stream>>>(W2, W2t, DHID, LL, DHID);

    // layer-0 gate sums
    gmean_part<<<dim3(BB, 8), 384, 0, stream>>>(T, G8);
    gmean_red<<<BB, 384, 0, stream>>>(G8, G);

    for (int l = 0; l < NLAYERS; ++l) {
        gating_kernel<<<1, 512, 0, stream>>>(G, wg + (size_t)l * LL * EE, wn + (size_t)l * LL * EE,
                                             noise + (size_t)l * BB * EE, IDX, GV, LOSS);
        fc1_mfma<<<1536, 256, 0, stream>>>(
            Tb16, W1t + (size_t)l * EE * DHID * LP, b1 + (size_t)l * EE * DHID, IDX, GV, Hs);
        fc2_mfma<<<1152, 256, 0, stream>>>(
            Hs, W2t + (size_t)l * EE * LL * DHID, b2 + (size_t)l * EE * LL, T, IDX, GV);
        t2b16_kernel<<<dim3(11, BB), 256, 0, stream>>>(T, Tb16, G);
    }
    proj_fused<<<321, 256, 0, stream>>>(Tb16, p1wb, p1b, p2wb, p2b, out);
    loss_write_kernel<<<1, 64, 0, stream>>>(LOSS, out);
}